// Round 9
// baseline (516.571 us; speedup 1.0000x reference)
//
#include <hip/hip_runtime.h>
#include <hip/hip_bf16.h>
#include <cstddef>
#include <cstdint>

#define PTOT 32768   // 8 * 64 * 64 pixels
#define HWSZ 4096

typedef __attribute__((ext_vector_type(8))) short bf16x8;
typedef __attribute__((ext_vector_type(4))) short s16x4;
typedef __attribute__((ext_vector_type(4))) float f32x4;

__device__ __forceinline__ float sigf(float x){ return 1.f/(1.f+__expf(-x)); }
__device__ __forceinline__ float siluf(float x){ return x*sigf(x); }
__device__ __forceinline__ short f2b(float x){
  __hip_bfloat16 h = __float2bfloat16(x);
  return *reinterpret_cast<short*>(&h);
}
__device__ __forceinline__ float b2f(short s){
  unsigned u = ((unsigned)(unsigned short)s) << 16;
  return __uint_as_float(u);
}

// async global->LDS, 16B per lane. LDS dest = wave-uniform base + lane*16.
__device__ __forceinline__ void gload16(const void* g, void* l){
  __builtin_amdgcn_global_load_lds(
      (const __attribute__((address_space(1))) unsigned int*)g,
      (__attribute__((address_space(3))) unsigned int*)l, 16, 0, 0);
}

// ---------------- weight conversion f32 -> bf16 ----------------
// layout: [sc_w1|mc_w](768x512) @0 ; sc_w2(256x512) @393216 ; qkvW(513x256) @524288 ; outp(512x512) @655616
__global__ __launch_bounds__(256) void k_cvtw(
    const float* __restrict__ s0, const float* __restrict__ s1, const float* __restrict__ s2,
    const float* __restrict__ s3, const float* __restrict__ s4,
    short* __restrict__ dst){
  int idx = blockIdx.x*256 + threadIdx.x;
  const float* s; int off;
  if      (idx <  262144){ s=s0; off=idx; }
  else if (idx <  393216){ s=s1; off=idx- 262144; }
  else if (idx <  524288){ s=s2; off=idx- 393216; }
  else if (idx <  655616){ s=s3; off=idx- 524288; }
  else if (idx <  917760){ s=s4; off=idx- 655616; }
  else return;
  dst[idx] = f2b(s[off]);
}

// ---------------- weight composition (linear-linear fusion) + bias concat ----------------
__global__ __launch_bounds__(256) void k_wcomp(
    const float* __restrict__ qkvHw, const float* __restrict__ fuWw,
    const float* __restrict__ fuWb,  const float* __restrict__ qkvHb,
    const float* __restrict__ inpw,  const float* __restrict__ fuHw,
    const float* __restrict__ fuHb,
    const float* __restrict__ scb1,  const float* __restrict__ mcb,
    short* __restrict__ wcomb, float* __restrict__ bcomb,
    short* __restrict__ wi2,   float* __restrict__ bi2,
    float* __restrict__ bzx)
{
  int blk = blockIdx.x;
  int tid = threadIdx.x;
  __shared__ float as[256];
  __shared__ float red[256];
  if (blk < 513){
    int i = blk;
    int r = (i==512) ? 0 : (i+1);
    as[tid]  = qkvHw[(size_t)r*256 + tid];
    red[tid] = as[tid] * fuWb[tid];
    __syncthreads();
    for (int off=128; off; off>>=1){ if (tid<off) red[tid]+=red[tid+off]; __syncthreads(); }
    float acc = 0.f;
    #pragma unroll 8
    for (int k=0;k<256;k++) acc += as[k]*fuWw[(size_t)k*256 + tid];
    wcomb[(size_t)(256+i)*256 + tid] = f2b(acc);
    if (tid==0) bcomb[256+i] = red[0] + qkvHb[r];
  } else if (blk < 769){
    int j = blk - 513;
    wcomb[(size_t)j*256 + tid] = f2b(fuWw[(size_t)j*256 + tid]);
    if (tid==0) bcomb[j] = fuWb[j];
  } else if (blk < 1283){
    int j = blk - 769;   // 0..513
    as[tid]  = inpw[(size_t)j*256 + tid];
    red[tid] = as[tid] * fuHb[tid];
    __syncthreads();
    for (int off=128; off; off>>=1){ if (tid<off) red[tid]+=red[tid+off]; __syncthreads(); }
    float acc = 0.f;
    #pragma unroll 8
    for (int k=0;k<256;k++) acc += as[k]*fuHw[(size_t)k*256 + tid];
    wi2[(size_t)j*256 + tid] = f2b(acc);
    if (tid==0) bi2[j] = red[0];
  } else {
    int j = (blk - 1283)*256 + tid;   // 0..767
    bzx[j] = (j < 512) ? scb1[j] : mcb[j-512];
  }
}

// ---------------- NCHW f32 -> pixel-major bf16 transpose ----------------
__global__ __launch_bounds__(256) void k_transpose(const float* __restrict__ in, short* __restrict__ out){
  __shared__ float tile[64][33];
  int b = blockIdx.z;
  int c0 = blockIdx.y * 64;
  int s0 = blockIdx.x * 32;
  int tx = threadIdx.x, ty = threadIdx.y;
  const float* ip = in + ((size_t)b*512 + c0)*HWSZ + s0;
  for (int i = ty; i < 64; i += 8) tile[i][tx] = ip[(size_t)i*HWSZ + tx];
  __syncthreads();
  for (int i = ty; i < 32; i += 8){
    unsigned lo = (unsigned)(unsigned short)f2b(tile[2*tx][i]);
    unsigned hi = (unsigned)(unsigned short)f2b(tile[2*tx+1][i]);
    unsigned pk = lo | (hi<<16);
    *reinterpret_cast<unsigned*>(&out[((size_t)((b<<12) + s0 + i))*512 + c0 + 2*tx]) = pk;
  }
}

// ---------------- bf16 MFMA GEMM: m97-style single-buffer A-LDS, W direct to registers -------
// C[m,n] = sum_k A(m,k)*W[n,k]; A = two-pointer concat (kSplit multiple of 32).
// W is L2/L3-hot: each lane loads its 16B fragment W[wn][k0+lh*8] directly, no LDS.
// qkvPerm: weight/bias row = (n==512)?0:n+1. Dual output: cols >= nSplit2 go to Cp2 (ldc2).
template<int ACT, int OUT_NCHW>
__global__ __launch_bounds__(256, 4) void k_gemm(
    const short* __restrict__ A0, const short* __restrict__ A1,
    int kSplit, int lda0, int lda1,
    const short* __restrict__ Wt, const float* __restrict__ bias,
    void* __restrict__ Cpv, int N, int K, int ldc, int qkvPerm,
    short* __restrict__ Cp2, int nSplit2, int ldc2)
{
  __shared__ short Alds[128*32];   // 8 KB, linear 64B rows

  int tid = threadIdx.x;
  int lane = tid & 63;
  int wv = tid >> 6;
  int wr = wv >> 1, wc = wv & 1;
  int lr = lane & 15, lh = lane >> 4;
  int bm = blockIdx.x * 128;
  int bn = blockIdx.y * 128;

  int rl = lane >> 2;        // row within a 16-row staging chunk
  int kg = (lane & 3) << 3;  // k element offset 0/8/16/24

  // A staging per-lane base pointers (k-invariant)
  const short* aB0[2];
  const short* aB1[2];
  #pragma unroll
  for (int j=0;j<2;j++){
    int m = bm + wv*32 + j*16 + rl;
    aB0[j] = A0 + (size_t)m*lda0 + kg;
    aB1[j] = A1 + (size_t)m*lda1 + kg;
  }
  // W fragment per-lane base pointers (k-invariant); clamp OOB rows
  const short* wB[4];
  #pragma unroll
  for (int ni=0;ni<4;ni++){
    int n = bn + wc*64 + ni*16 + lr;
    if (n > N-1) n = N-1;
    int wn = qkvPerm ? ((n==512)?0:(n+1)) : n;
    wB[ni] = Wt + (size_t)wn*K + lh*8;
  }

  f32x4 acc[4][4];
  #pragma unroll
  for (int i=0;i<4;i++)
    #pragma unroll
    for (int j=0;j<4;j++) acc[i][j] = (f32x4){0.f,0.f,0.f,0.f};

  for (int k0 = 0; k0 < K; k0 += 32){
    // issue W register loads (L2-hot) first for overlap
    bf16x8 bfr[4];
    #pragma unroll
    for (int ni=0;ni<4;ni++)
      bfr[ni] = *reinterpret_cast<const bf16x8*>(wB[ni] + k0);
    // stage A tile (async to LDS)
    {
      const short* s0;
      const short* s1;
      if (k0 < kSplit){ s0 = aB0[0] + k0; s1 = aB0[1] + k0; }
      else            { s0 = aB1[0] + (k0 - kSplit); s1 = aB1[1] + (k0 - kSplit); }
      gload16(s0, &Alds[(wv*32)*32]);
      gload16(s1, &Alds[(wv*32 + 16)*32]);
    }
    __syncthreads();   // drains vmcnt -> A tile visible
    bf16x8 af[4];
    #pragma unroll
    for (int mi=0;mi<4;mi++)
      af[mi] = *reinterpret_cast<const bf16x8*>(&Alds[(wr*64 + mi*16 + lr)*32 + lh*8]);
    #pragma unroll
    for (int mi=0;mi<4;mi++)
      #pragma unroll
      for (int ni=0;ni<4;ni++)
        acc[mi][ni] = __builtin_amdgcn_mfma_f32_16x16x32_bf16(af[mi], bfr[ni], acc[mi][ni], 0, 0, 0);
    __syncthreads();   // readers done before next stage overwrites
  }

  if (!OUT_NCHW){
    short* Cp = (short*)Cpv;
    #pragma unroll
    for (int mi=0;mi<4;mi++){
      int m = bm + wr*64 + mi*16 + lh*4;
      #pragma unroll
      for (int ni=0;ni<4;ni++){
        int n = bn + wc*64 + ni*16 + lr;
        if (n < N){
          int wn = qkvPerm ? ((n==512)?0:(n+1)) : n;
          float bb = bias ? bias[wn] : 0.f;
          #pragma unroll
          for (int r=0;r<4;r++){
            float v = acc[mi][ni][r] + bb;
            if (ACT==1) v = siluf(v);
            short sv = f2b(v);
            if (n < nSplit2) Cp[(size_t)(m+r)*ldc + n] = sv;
            else             Cp2[(size_t)(m+r)*ldc2 + (n - nSplit2)] = sv;
          }
        }
      }
    }
  } else {
    // bulk transpose per wave through LDS scratch: [16 m][64 n] f32, stride 68
    float* Cp = (float*)Cpv;
    __shared__ float S[4][16][68];
    float* Sep = &S[wv][0][0];
    #pragma unroll
    for (int mi=0;mi<4;mi++){
      __syncthreads();
      #pragma unroll
      for (int ni=0;ni<4;ni++){
        int n = bn + wc*64 + ni*16 + lr;
        float bb = (bias && n < N) ? bias[n] : 0.f;
        #pragma unroll
        for (int r=0;r<4;r++){
          float v = acc[mi][ni][r] + bb;
          if (ACT==1) v = siluf(v);
          Sep[(lh*4+r)*68 + ni*16 + lr] = v;
        }
      }
      __syncthreads();
      int m = bm + wr*64 + mi*16 + lr;
      size_t mb = ((size_t)(m>>12)*ldc)*HWSZ + (m & 4095);
      #pragma unroll
      for (int g=0; g<16; g++){
        int nl = g*4 + lh;
        float v = Sep[lr*68 + nl];
        int nn = bn + wc*64 + nl;
        if (nn < N) Cp[mb + (size_t)nn*HWSZ] = v;
      }
    }
  }
}

// ---------------- depthwise 3x3 SAME + silu, pixel-major bf16 [P][512] ----------------
__global__ __launch_bounds__(256) void k_dwconv3x3(const short* __restrict__ in,
    const float* __restrict__ w, const float* __restrict__ bias, short* __restrict__ out){
  int tid = threadIdx.x;
  int cq = tid & 127;
  int wi = tid >> 7;
  int bw = blockIdx.x;              // b*32 + wpair
  int b  = bw >> 5;
  int wc = ((bw & 31) << 1) | wi;   // 0..63
  int h0 = blockIdx.y << 4;
  int c  = cq << 2;

  float arr[36];
  {
    const float* wp = &w[c*9];
    #pragma unroll
    for (int t=0;t<9;t++){
      f32x4 v = *reinterpret_cast<const f32x4*>(wp + t*4);
      arr[t*4+0]=v[0]; arr[t*4+1]=v[1]; arr[t*4+2]=v[2]; arr[t*4+3]=v[3];
    }
  }
  f32x4 bias4 = *reinterpret_cast<const f32x4*>(&bias[c]);

  int pb = b << 12;
  auto ldrow = [&](int r, int dw)->f32x4 {
    int ww = wc + dw;
    if ((unsigned)r >= 64u || (unsigned)ww >= 64u) return (f32x4){0.f,0.f,0.f,0.f};
    s16x4 v = *reinterpret_cast<const s16x4*>(&in[((size_t)(pb + (r<<6) + ww) << 9) + c]);
    return (f32x4){b2f(v[0]), b2f(v[1]), b2f(v[2]), b2f(v[3])};
  };

  f32x4 a00,a01,a02,a10,a11,a12,a20,a21,a22;
  a00=ldrow(h0-1,-1); a01=ldrow(h0-1,0); a02=ldrow(h0-1,1);
  a10=ldrow(h0  ,-1); a11=ldrow(h0  ,0); a12=ldrow(h0  ,1);
  #pragma unroll
  for (int hh=0; hh<16; hh++){
    int h = h0 + hh;
    a20=ldrow(h+1,-1); a21=ldrow(h+1,0); a22=ldrow(h+1,1);
    s16x4 o;
    #pragma unroll
    for (int j=0;j<4;j++){
      float v = bias4[j];
      v = fmaf(a00[j], arr[j*9+0], v);
      v = fmaf(a01[j], arr[j*9+1], v);
      v = fmaf(a02[j], arr[j*9+2], v);
      v = fmaf(a10[j], arr[j*9+3], v);
      v = fmaf(a11[j], arr[j*9+4], v);
      v = fmaf(a12[j], arr[j*9+5], v);
      v = fmaf(a20[j], arr[j*9+6], v);
      v = fmaf(a21[j], arr[j*9+7], v);
      v = fmaf(a22[j], arr[j*9+8], v);
      o[j] = f2b(siluf(v));
    }
    *reinterpret_cast<s16x4*>(&out[((size_t)(pb + (h<<6) + wc) << 9) + c]) = o;
    a00=a10; a01=a11; a02=a12;
    a10=a20; a11=a21; a12=a22;
  }
}

// ---------------- axis attention: layout k@0, v@+256, q@+512 within qkv (stride qld) --------
__global__ __launch_bounds__(256) void k_attn(const short* __restrict__ x, int xld,
    const short* __restrict__ qkv, int qld, short* __restrict__ out, int axisH){
  int bl = blockIdx.x;          // 0..511
  int b = bl >> 6, line = bl & 63;
  __shared__ float es[64];
  __shared__ float qs[64];
  int tid = threadIdx.x;
  int pbase = b << 12;
  if (tid < 64){
    int p = axisH ? (pbase | (tid<<6) | line) : (pbase | (line<<6) | tid);
    qs[tid] = b2f(qkv[(size_t)p*qld + 512]);
  }
  __syncthreads();
  float mx = -1e30f;
  for (int t=0;t<64;t++) mx = fmaxf(mx, qs[t]);
  if (tid < 64) es[tid] = __expf(qs[tid]-mx);
  __syncthreads();
  float s = 0.f;
  for (int t=0;t<64;t++) s += es[t];
  float inv = 1.f/s;
  int c = tid;                 // 256 channels
  float ctx = 0.f;
  for (int t=0;t<64;t++){
    int p = axisH ? (pbase | (t<<6) | line) : (pbase | (line<<6) | t);
    ctx += es[t]*b2f(qkv[(size_t)p*qld + c]);
  }
  ctx *= inv;
  for (int t=0;t<64;t++){
    int p = axisH ? (pbase | (t<<6) | line) : (pbase | (line<<6) | t);
    float vv = b2f(qkv[(size_t)p*qld + 256 + c]);
    float xv = b2f(x[(size_t)p*xld + c]);
    out[(size_t)p*256 + c] = f2b(xv + sigf(vv)*ctx);
  }
}

// ---------------- dt = softplus(xbcdt[:,512:514] + dt_bias) ----------------
__global__ __launch_bounds__(256) void k_dt(const short* __restrict__ xbcdt,
    const float* __restrict__ dt_bias, float* __restrict__ dtb){
  int idx = blockIdx.x*256 + threadIdx.x;   // P*2
  if (idx >= PTOT*2) return;
  int p = idx >> 1, h = idx & 1;
  float xv = b2f(xbcdt[(size_t)p*520 + 512 + h]) + dt_bias[h];
  float sp = (xv > 20.f) ? xv : log1pf(__expf(xv));
  dtb[idx] = sp;
}

// ---------------- causal depthwise conv1d (k=4) + silu, bf16 ----------------
__global__ __launch_bounds__(256) void k_conv1d(const short* __restrict__ xbcdt,
    const float* __restrict__ w, const float* __restrict__ bias, short* __restrict__ xBC){
  int tid = threadIdx.x;
  int cq = tid & 127;
  int c  = cq << 2;
  int half = tid >> 7;
  int bs = blockIdx.x;              // b*128 + strip-pair
  int b  = bs >> 7;
  int t0 = ((((bs & 127) << 1) | half) << 4);

  float wk[16];
  {
    const float* wp = &w[c*4];
    #pragma unroll
    for (int t=0;t<4;t++){
      f32x4 v = *reinterpret_cast<const f32x4*>(wp + t*4);
      wk[t*4+0]=v[0]; wk[t*4+1]=v[1]; wk[t*4+2]=v[2]; wk[t*4+3]=v[3];
    }
  }
  f32x4 bias4 = *reinterpret_cast<const f32x4*>(&bias[c]);

  int pb = b << 12;
  auto ld = [&](int t)->f32x4 {
    if (t < 0) return (f32x4){0.f,0.f,0.f,0.f};
    s16x4 v = *reinterpret_cast<const s16x4*>(&xbcdt[(size_t)(pb + t)*520 + c]);
    return (f32x4){b2f(v[0]), b2f(v[1]), b2f(v[2]), b2f(v[3])};
  };

  f32x4 x0,x1,x2,x3;
  x0 = ld(t0-3); x1 = ld(t0-2); x2 = ld(t0-1);
  #pragma unroll
  for (int tt=0; tt<16; tt++){
    int t = t0 + tt;
    x3 = ld(t);
    s16x4 o;
    #pragma unroll
    for (int j=0;j<4;j++){
      float v = bias4[j];
      v = fmaf(x0[j], wk[j*4+0], v);
      v = fmaf(x1[j], wk[j*4+1], v);
      v = fmaf(x2[j], wk[j*4+2], v);
      v = fmaf(x3[j], wk[j*4+3], v);
      o[j] = f2b(siluf(v));
    }
    *reinterpret_cast<s16x4*>(&xBC[((size_t)(pb + t) << 9) + c]) = o;
    x0=x1; x1=x2; x2=x3;
  }
}

// ---------------- SSD: per-(chunk,head,batch) cumsum + chunk states [64n x 128p] -------------
__global__ __launch_bounds__(256) void k_ssd_states(
  const short* __restrict__ xBC, const float* __restrict__ dtb, const float* __restrict__ A_log,
  float* __restrict__ states, float* __restrict__ AcsG, float* __restrict__ AtotG)
{
  int ci = blockIdx.x, h = blockIdx.y, b = blockIdx.z;
  int tid = threadIdx.x;
  __shared__ float sa[256], sb[256];
  __shared__ float Bs[64][65];
  __shared__ float Xs[64][136];
  int base = (b<<12) | (ci<<8);
  float Ah = -__expf(A_log[h]);
  sa[tid] = dtb[(size_t)(base + tid)*2 + h] * Ah;
  __syncthreads();
  float* src = sa; float* dst = sb;
  for (int off=1; off<256; off<<=1){
    float v = src[tid];
    if (tid >= off) v += src[tid - off];
    dst[tid] = v;
    __syncthreads();
    float* tswap = src; src = dst; dst = tswap;
  }
  float acs = src[tid];
  float atot = src[255];
  AcsG[((size_t)((b*2+h)*16 + ci))*256 + tid] = acs;
  if (tid == 0) AtotG[(b*2+h)*16 + ci] = atot;

  int tn = tid >> 4;   // n group
  int tp = tid & 15;   // p group
  float acc[4][8];
  #pragma unroll
  for (int i=0;i<4;i++)
    #pragma unroll
    for (int j=0;j<8;j++) acc[i][j]=0.f;

  for (int t0=0; t0<256; t0+=64){
    __syncthreads();
    for (int e = tid; e < 64*64; e += 256){
      int t = e >> 6, n = e & 63;
      float d = __expf(atot - src[t0 + t]);
      Bs[t][n] = b2f(xBC[(size_t)(base + t0 + t)*512 + 256 + (h<<6) + n]) * d;
    }
    for (int e = tid; e < 64*128; e += 256){
      int t = e >> 7, pp = e & 127;
      Xs[t][pp] = b2f(xBC[(size_t)(base + t0 + t)*512 + (h<<7) + pp]) * dtb[(size_t)(base + t0 + t)*2 + h];
    }
    __syncthreads();
    for (int t=0;t<64;t++){
      float bv[4], xv[8];
      #pragma unroll
      for (int i=0;i<4;i++) bv[i]=Bs[t][tn*4+i];
      #pragma unroll
      for (int j=0;j<8;j++) xv[j]=Xs[t][tp*8+j];
      #pragma unroll
      for (int i=0;i<4;i++)
        #pragma unroll
        for (int j=0;j<8;j++) acc[i][j] = fmaf(bv[i], xv[j], acc[i][j]);
    }
  }
  float* stp = states + (((size_t)(b*16+ci)*2 + h) << 13);
  #pragma unroll
  for (int i=0;i<4;i++){
    float4 s0 = {acc[i][0], acc[i][1], acc[i][2], acc[i][3]};
    float4 s1 = {acc[i][4], acc[i][5], acc[i][6], acc[i][7]};
    float* pdst = &stp[(tn*4+i)*128 + tp*8];
    *reinterpret_cast<float4*>(pdst)   = s0;
    *reinterpret_cast<float4*>(pdst+4) = s1;
  }
}

// ---------------- inter-chunk scan ----------------
__global__ __launch_bounds__(256) void k_ssd_scan(const float* __restrict__ states,
    const float* __restrict__ AtotG, float* __restrict__ R){
  int bh = blockIdx.x;   // b*2+h
  int b = bh >> 1, h = bh & 1;
  int tid = threadIdx.x;
  float r[32];
  #pragma unroll
  for (int j=0;j<32;j++) r[j]=0.f;
  for (int ci=0; ci<16; ci++){
    size_t off = (((size_t)(b*16+ci)*2) + h) << 13;
    #pragma unroll
    for (int j=0;j<32;j++) R[off + tid + (j<<8)] = r[j];
    if (ci < 15){
      float sc = __expf(AtotG[bh*16 + ci]);
      #pragma unroll
      for (int j=0;j<32;j++) r[j] = fmaf(sc, r[j], states[off + tid + (j<<8)]);
    }
  }
}

// ---------------- SSD Y (bf16 MFMA) ----------------
__global__ __launch_bounds__(256) void k_ssd_y(
  const short* __restrict__ xBC, const float* __restrict__ dtb,
  const float* __restrict__ AcsG, const float* __restrict__ R,
  const float* __restrict__ Dp, float* __restrict__ yraw)
{
  int bx = blockIdx.x;
  int ci = bx >> 2, lt = bx & 3;
  int h = blockIdx.y, b = blockIdx.z;
  int tid = threadIdx.x, lane = tid & 63, w = tid >> 6;
  int lg = lane >> 4, lr = lane & 15;
  int base = (b<<12) | (ci<<8);
  int l0 = lt << 6;

  __shared__ short Cbf[64*72];   // [l][n]  stride 72 bf16 (144B)
  __shared__ short Bbf[64*72];   // [s][n]
  __shared__ short Xt [128*76];  // [p][s] transposed, stride 76; reused for R^T [p][n]
  __shared__ short Sbf[64*72];   // [l][s]
  __shared__ float acs_l[64], acs_s[64], dt_s[64];

  const float* acsrow = AcsG + ((size_t)((b*2+h)*16 + ci))*256;

  // ---- stage C: 64 l-rows x 64 n (pure copy)
  {
    int row = tid >> 2, c0 = (tid & 3) << 4;
    const short* src = &xBC[(size_t)(base + l0 + row)*512 + 384 + (h<<6) + c0];
    *reinterpret_cast<bf16x8*>(&Cbf[row*72 + c0])     = *reinterpret_cast<const bf16x8*>(src);
    *reinterpret_cast<bf16x8*>(&Cbf[row*72 + c0 + 8]) = *reinterpret_cast<const bf16x8*>(src+8);
  }
  if (tid < 64) acs_l[tid] = acsrow[l0 + tid];

  f32x4 yacc[8];
  #pragma unroll
  for (int pf=0;pf<8;pf++) yacc[pf] = (f32x4){0.f,0.f,0.f,0.f};

  for (int s0 = 0; s0 <= l0; s0 += 64){
    __syncthreads();   // prev-iter readers done before restaging Bbf/Xt
    // ---- stage B (pure copy)
    {
      int row = tid >> 2, c0 = (tid & 3) << 4;
      const short* src = &xBC[(size_t)(base + s0 + row)*512 + 256 + (h<<6) + c0];
      *reinterpret_cast<bf16x8*>(&Bbf[row*72 + c0])     = *reinterpret_cast<const bf16x8*>(src);
      *reinterpret_cast<bf16x8*>(&Bbf[row*72 + c0 + 8]) = *reinterpret_cast<const bf16x8*>(src+8);
    }
    // ---- stage X transposed: Xt[p][s]
    {
      int s = tid >> 2;
      int p0 = (tid & 3) << 5;
      const short* src = &xBC[(size_t)(base + s0 + s)*512 + (h<<7) + p0];
      #pragma unroll
      for (int q=0;q<4;q++){
        bf16x8 v = *reinterpret_cast<const bf16x8*>(src + q*8);
        #pragma unroll
        for (int e=0;e<8;e++) Xt[(p0 + q*8 + e)*76 + s] = v[e];
      }
    }
    if (tid < 64){
      acs_s[tid] = acsrow[s0 + tid];
      dt_s[tid]  = dtb[(size_t)(base + s0 + tid)*2 + h];
    }
    __syncthreads();

    // ---- scores: sacc[f] = C(wave's 16 l) x B^T (64 s), K=n=64
    f32x4 sacc[4];
    #pragma unroll
    for (int f=0;f<4;f++) sacc[f] = (f32x4){0.f,0.f,0.f,0.f};
    bf16x8 ca0 = *reinterpret_cast<const bf16x8*>(&Cbf[(w*16+lr)*72 + lg*8]);
    bf16x8 ca1 = *reinterpret_cast<const bf16x8*>(&Cbf[(w*16+lr)*72 + 32 + lg*8]);
    #pragma unroll
    for (int f=0;f<4;f++){
      bf16x8 bb0 = *reinterpret_cast<const bf16x8*>(&Bbf[(f*16+lr)*72 + lg*8]);
      bf16x8 bb1 = *reinterpret_cast<const bf16x8*>(&Bbf[(f*16+lr)*72 + 32 + lg*8]);
      sacc[f] = __builtin_amdgcn_mfma_f32_16x16x32_bf16(ca0, bb0, sacc[f], 0, 0, 0);
      sacc[f] = __builtin_amdgcn_mfma_f32_16x16x32_bf16(ca1, bb1, sacc[f], 0, 0, 0);
    }
    // ---- mask * decay * dt -> Sbf[l][s] (bf16)
    #pragma unroll
    for (int f=0;f<4;f++){
      #pragma unroll
      for (int r=0;r<4;r++){
        int ll = w*16 + lg*4 + r;
        int ss = f*16 + lr;
        float v = 0.f;
        if (s0 + ss <= l0 + ll)
          v = sacc[f][r] * __expf(acs_l[ll] - acs_s[ss]) * dt_s[ss];
        Sbf[ll*72 + ss] = f2b(v);
      }
    }
    __syncthreads();

    // ---- Y += S' @ Xraw
    bf16x8 sa0 = *reinterpret_cast<const bf16x8*>(&Sbf[(w*16+lr)*72 + lg*8]);
    bf16x8 sa1 = *reinterpret_cast<const bf16x8*>(&Sbf[(w*16+lr)*72 + 32 + lg*8]);
    #pragma unroll
    for (int pf=0;pf<8;pf++){
      bf16x8 x0 = *reinterpret_cast<const bf16x8*>(&Xt[(pf*16+lr)*76 + lg*8]);
      bf16x8 x1 = *reinterpret_cast<const bf16x8*>(&Xt[(pf*16+lr)*76 + 32 + lg*8]);
      yacc[pf] = __builtin_amdgcn_mfma_f32_16x16x32_bf16(sa0, x0, yacc[pf], 0, 0, 0);
      yacc[pf] = __builtin_amdgcn_mfma_f32_16x16x32_bf16(sa1, x1, yacc[pf], 0, 0, 0);
    }
  }

  // ---- R term: restage Xt <- R^T  (R is f32 [n=64][p=128])
  __syncthreads();
  {
    size_t roff = (((size_t)(b*16+ci)*2) + h) << 13;
    int n = tid >> 2;
    const float* src = R + roff + (size_t)n*128;
    #pragma unroll
    for (int j=0;j<8;j++){
      int p = ((tid & 3) << 2) + (j << 4);
      float4 f = *reinterpret_cast<const float4*>(&src[p]);
      Xt[(p+0)*76 + n] = f2b(f.x);
      Xt[(p+1)*76 + n] = f2b(f.y);
      Xt[(p+2)*76 + n] = f2b(f.z);
      Xt[(p+3)*76 + n] = f2b(f.w);
    }
  }
  __syncthreads();
  f32x4 racc[8];
  #pragma unroll
  for (int pf=0;pf<8;pf++) racc[pf] = (f32x4){0.f,0.f,0.f,0.f};
  {
    bf16x8 ca0 = *reinterpret_cast<const bf16x8*>(&Cbf[(w*16+lr)*72 + lg*8]);
    bf16x8 ca1 = *reinterpret_cast<const bf16x8*>(&Cbf[(w*16+lr)*72 + 32 + lg*8]);
    #pragma unroll
    for (int pf=0;pf<8;pf++){
      bf16x8 x0 = *reinterpret_cast<const bf16x8*>(&Xt[(pf*16+lr)*76 + lg*8]);
      bf16x8 x1 = *reinterpret_cast<const bf16x8*>(&Xt[(pf*16+lr)*76 + 32 + lg*8]);
      racc[pf] = __builtin_amdgcn_mfma_f32_16x16x32_bf16(ca0, x0, racc[pf], 0, 0, 0);
      racc[pf] = __builtin_amdgcn_mfma_f32_16x16x32_bf16(ca1, x1, racc[pf], 0, 0, 0);
    }
  }

  // ---- epilogue: y = yacc + exp(acs_l)*racc + D*Xraw
  float Dh = Dp[h];
  float el[4];
  #pragma unroll
  for (int r=0;r<4;r++) el[r] = __expf(acs_l[w*16 + lg*4 + r]);
  #pragma unroll
  for (int pf=0;pf<8;pf++){
    #pragma unroll
    for (int r=0;r<4;r++){
      int ll = w*16 + lg*4 + r;
      int p = pf*16 + lr;
      size_t pix = (size_t)(base + l0 + ll);
      float xraw = b2f(xBC[pix*512 + (h<<7) + p]);
      yraw[pix*256 + (h<<7) + p] = yacc[pf][r] + el[r]*racc[pf][r] + Dh*xraw;
    }
  }
}

// ---------------- RMSNorm over 256 channels per pixel (f32 in, bf16 out) ----------------
__global__ __launch_bounds__(256) void k_rmsnorm(const float* __restrict__ yraw,
    const float* __restrict__ nw, short* __restrict__ ynorm){
  int p = blockIdx.x;
  int tid = threadIdx.x;
  float v = yraw[(size_t)p*256 + tid];
  float sq = v*v;
  for (int off=32; off; off>>=1) sq += __shfl_down(sq, off);
  __shared__ float wsum[4];
  if ((tid & 63) == 0) wsum[tid>>6] = sq;
  __syncthreads();
  float tot = wsum[0]+wsum[1]+wsum[2]+wsum[3];
  float scale = rsqrtf(tot*(1.f/256.f) + 1e-5f);
  ynorm[(size_t)p*256 + tid] = f2b(v*scale*nw[tid]);
}

// =====================================================================================
extern "C" void kernel_launch(void* const* d_in, const int* in_sizes, int n_in,
                              void* d_out, int out_size, void* d_ws, size_t ws_size,
                              hipStream_t stream)
{
  (void)in_sizes; (void)n_in; (void)out_size; (void)ws_size;
  const float* u        = (const float*)d_in[0];
  const float* sc_w1    = (const float*)d_in[1];
  const float* sc_b1    = (const float*)d_in[2];
  const float* sc_wdw   = (const float*)d_in[3];
  const float* sc_bdw   = (const float*)d_in[4];
  const float* sc_w2    = (const float*)d_in[5];
  const float* sc_b2    = (const float*)d_in[6];
  const float* mc_w     = (const float*)d_in[7];
  const float* mc_b     = (const float*)d_in[8];
  const float* qkvW_w   = (const float*)d_in[9];
  const float* qkvW_b   = (const float*)d_in[10];
  const float* qkvH_w   = (const float*)d_in[11];
  const float* qkvH_b   = (const float*)d_in[12];
  const float* fuseW_w  = (const float*)d_in[13];
  const float* fuseW_b  = (const float*)d_in[14];
  const float* fuseH_w  = (const float*)d_in[15];
  const float* fuseH_b  = (const float*)d_in[16];
  const float* in_proj_w= (const float*)d_in[17];
  const float* conv1d_w = (const float*)d_in[18];
  const float* conv1d_b = (const float*)d_in[19];
  const float* dt_bias  = (const float*)d_in[20];
  const float* A_log    = (const float*)d_in[21];
  const float* Dp       = (const float*)d_in[22];
  const float* norm_w   = (const float*)d_in[23];
  const float* outp_w   = (const float*)d_in[24];
  const float* outp_b   = (const float*)d_in[25];

  char* wsb = (char*)d_ws;
  size_t off = 0;
  auto alloc = [&](size_t bytes){ void* p = wsb + off; off = (off + bytes + 255) & ~(size_t)255; return p; };
  short* wbf   = (short*)alloc((size_t)1246208*2);    // w_zx|w_sc2|w_qkvW|w_outp|wcomb|wi2
  float* bcomb = (float*)alloc(769*4);
  float* bi2   = (float*)alloc(514*4);
  float* bzx   = (float*)alloc(768*4);
  short* slotB = (short*)alloc((size_t)PTOT*776*2);   // z1(512) / qkvW(520) / merged(776) / xbcdt(520)
  short* slotC = (short*)alloc((size_t)PTOT*512*2);   // z1dw / xBC
  short* slotZ = (short*)alloc((size_t)PTOT*256*2);   // z
  short* slotE = (short*)alloc((size_t)PTOT*256*2);   // x1; later ynorm
  float* slotF = (float*)alloc((size_t)PTOT*256*4);   // xw/xh (bf16, front) ; later yraw (f32)
  float* slotS = (float*)alloc((size_t)4460000*4);    // SSD f32 scratch

  float* dtb     = slotS;                    // P*2      = 65536
  float* AcsG    = slotS + 65536;            // 65536
  float* AtotG   = slotS + 131072;           // 256
  float* statesB = slotS + 131328;           // 2097152
  float* Rb      = slotS + 131328 + 2097152; // 2097152
  short* ynorm   = slotE;
  short* xwh     = (short*)slotF;            // bf16 view for attn outputs

  // weight table (element offsets into wbf)
  short* w_zx   = wbf + 0;         // 768 x 512  [sc_w1 ; mc_w]
  short* w_sc2  = wbf + 393216;    // 256 x 512
  short* w_qkvW = wbf + 524288;    // 513 x 256
  short* w_outp = wbf + 655616;    // 512 x 512
  short* wcomb  = wbf + 917760;    // 769 x 256
  short* wi2    = wbf + 1114624;   // 514 x 256

  short* u_pm = (short*)d_out;  // d_out doubles as bf16 pixel-major u scratch (32MB of 64MB)
  float* out  = (float*)d_out;

  const int BIG = 1<<30;

  k_cvtw<<<3585, 256, 0, stream>>>(sc_w1, mc_w, sc_w2, qkvW_w, outp_w, wbf);
  k_wcomp<<<1286, 256, 0, stream>>>(qkvH_w, fuseW_w, fuseW_b, qkvH_b, in_proj_w, fuseH_w, fuseH_b,
                                    sc_b1, mc_b, wcomb, bcomb, wi2, bi2, bzx);
  k_transpose<<<dim3(128,8,8), dim3(32,8), 0, stream>>>(u, u_pm);

  // merged z1 + x1: N=768, dual output (z1 -> slotB ld512; x1 -> slotE ld256)
  k_gemm<1,0><<<dim3(256,6), 256, 0, stream>>>(u_pm, u_pm, BIG, 512, 512, w_zx, bzx,
                                               slotB, 768, 512, 512, 0, slotE, 512, 256);
  // z-branch
  k_dwconv3x3<<<dim3(256,4), 256, 0, stream>>>(slotB, sc_wdw, sc_bdw, slotC);
  k_gemm<1,0><<<dim3(256,2), 256, 0, stream>>>(slotC, slotC, BIG, 512, 512, w_sc2, sc_b2,
                                               slotZ, 256, 512, 256, 0, nullptr, BIG, 0);

  // x-branch: qkv W: [k|v|q] stride 520
  k_gemm<0,0><<<dim3(256,5), 256, 0, stream>>>(slotE, slotE, BIG, 256, 256, w_qkvW, qkvW_b,
                                               slotB, 513, 256, 520, 1, nullptr, BIG, 0);
  k_attn<<<512, 256, 0, stream>>>(slotE, 256, slotB, 520, xwh, 0);
  // merged fuseW + (qkvH∘fuseW): [a2(256) | k|v|q(513)] stride 776
  k_gemm<0,0><<<dim3(256,7), 256, 0, stream>>>(xwh, xwh, BIG, 256, 256, wcomb, bcomb,
                                               slotB, 769, 256, 776, 0, nullptr, BIG, 0);
  k_attn<<<512, 256, 0, stream>>>(slotB, 776, slotB + 256, 776, xwh, 1);
  // composed in_proj: xbcdt [xBC(512) | dt(2)] stride 520
  k_gemm<0,0><<<dim3(256,5), 256, 0, stream>>>(xwh, xwh, BIG, 256, 256, wi2, bi2,
                                               slotB, 514, 256, 520, 0, nullptr, BIG, 0);
  k_dt<<<256, 256, 0, stream>>>(slotB, dt_bias, dtb);
  k_conv1d<<<1024, 256, 0, stream>>>(slotB, conv1d_w, conv1d_b, slotC);

  // SSD
  k_ssd_states<<<dim3(16,2,8), 256, 0, stream>>>(slotC, dtb, A_log, statesB, AcsG, AtotG);
  k_ssd_scan<<<16, 256, 0, stream>>>(statesB, AtotG, Rb);
  k_ssd_y<<<dim3(64,2,8), 256, 0, stream>>>(slotC, dtb, AcsG, Rb, Dp, slotF);

  // RMSNorm (f32 yraw -> bf16 ynorm in slotE)
  k_rmsnorm<<<32768, 256, 0, stream>>>(slotF, norm_w, ynorm);

  // final: out = concat(z, ynorm) @ outp_w^T + b, written f32 NCHW into d_out
  k_gemm<0,1><<<dim3(256,4), 256, 0, stream>>>(slotZ, ynorm, 256, 256, 256, w_outp, outp_b,
                                               out, 512, 512, 512, 0, nullptr, BIG, 0);
}

// Round 10
// 436.247 us; speedup vs baseline: 1.1841x; 1.1841x over previous
//
#include <hip/hip_runtime.h>
#include <hip/hip_bf16.h>
#include <cstddef>
#include <cstdint>

#define PTOT 32768   // 8 * 64 * 64 pixels
#define HWSZ 4096

typedef __attribute__((ext_vector_type(8))) short bf16x8;
typedef __attribute__((ext_vector_type(4))) short s16x4;
typedef __attribute__((ext_vector_type(4))) float f32x4;

__device__ __forceinline__ float sigf(float x){ return 1.f/(1.f+__expf(-x)); }
__device__ __forceinline__ float siluf(float x){ return x*sigf(x); }
__device__ __forceinline__ short f2b(float x){
  __hip_bfloat16 h = __float2bfloat16(x);
  return *reinterpret_cast<short*>(&h);
}
__device__ __forceinline__ float b2f(short s){
  unsigned u = ((unsigned)(unsigned short)s) << 16;
  return __uint_as_float(u);
}

// async global->LDS, 16B per lane. LDS dest = wave-uniform base + lane*16.
__device__ __forceinline__ void gload16(const void* g, void* l){
  __builtin_amdgcn_global_load_lds(
      (const __attribute__((address_space(1))) unsigned int*)g,
      (__attribute__((address_space(3))) unsigned int*)l, 16, 0, 0);
}

// ---------------- weight conversion f32 -> bf16 ----------------
__global__ __launch_bounds__(256) void k_cvtw(
    const float* __restrict__ s0, const float* __restrict__ s1, const float* __restrict__ s2,
    const float* __restrict__ s3, const float* __restrict__ s4,
    short* __restrict__ dst){
  int idx = blockIdx.x*256 + threadIdx.x;
  const float* s; int off;
  if      (idx <  262144){ s=s0; off=idx; }
  else if (idx <  393216){ s=s1; off=idx- 262144; }
  else if (idx <  524288){ s=s2; off=idx- 393216; }
  else if (idx <  655616){ s=s3; off=idx- 524288; }
  else if (idx <  917760){ s=s4; off=idx- 655616; }
  else return;
  dst[idx] = f2b(s[off]);
}

// ---------------- weight composition (linear-linear fusion) + bias concat ----------------
__global__ __launch_bounds__(256) void k_wcomp(
    const float* __restrict__ qkvHw, const float* __restrict__ fuWw,
    const float* __restrict__ fuWb,  const float* __restrict__ qkvHb,
    const float* __restrict__ inpw,  const float* __restrict__ fuHw,
    const float* __restrict__ fuHb,
    const float* __restrict__ scb1,  const float* __restrict__ mcb,
    short* __restrict__ wcomb, float* __restrict__ bcomb,
    short* __restrict__ wi2,   float* __restrict__ bi2,
    float* __restrict__ bzx)
{
  int blk = blockIdx.x;
  int tid = threadIdx.x;
  __shared__ float as[256];
  __shared__ float red[256];
  if (blk < 513){
    int i = blk;
    int r = (i==512) ? 0 : (i+1);
    as[tid]  = qkvHw[(size_t)r*256 + tid];
    red[tid] = as[tid] * fuWb[tid];
    __syncthreads();
    for (int off=128; off; off>>=1){ if (tid<off) red[tid]+=red[tid+off]; __syncthreads(); }
    float acc = 0.f;
    #pragma unroll 8
    for (int k=0;k<256;k++) acc += as[k]*fuWw[(size_t)k*256 + tid];
    wcomb[(size_t)(256+i)*256 + tid] = f2b(acc);
    if (tid==0) bcomb[256+i] = red[0] + qkvHb[r];
  } else if (blk < 769){
    int j = blk - 513;
    wcomb[(size_t)j*256 + tid] = f2b(fuWw[(size_t)j*256 + tid]);
    if (tid==0) bcomb[j] = fuWb[j];
  } else if (blk < 1283){
    int j = blk - 769;   // 0..513
    as[tid]  = inpw[(size_t)j*256 + tid];
    red[tid] = as[tid] * fuHb[tid];
    __syncthreads();
    for (int off=128; off; off>>=1){ if (tid<off) red[tid]+=red[tid+off]; __syncthreads(); }
    float acc = 0.f;
    #pragma unroll 8
    for (int k=0;k<256;k++) acc += as[k]*fuHw[(size_t)k*256 + tid];
    wi2[(size_t)j*256 + tid] = f2b(acc);
    if (tid==0) bi2[j] = red[0];
  } else {
    int j = (blk - 1283)*256 + tid;   // 0..767
    bzx[j] = (j < 512) ? scb1[j] : mcb[j-512];
  }
}

// ---------------- NCHW f32 -> pixel-major bf16 transpose ----------------
__global__ __launch_bounds__(256) void k_transpose(const float* __restrict__ in, short* __restrict__ out){
  __shared__ float tile[64][33];
  int b = blockIdx.z;
  int c0 = blockIdx.y * 64;
  int s0 = blockIdx.x * 32;
  int tx = threadIdx.x, ty = threadIdx.y;
  const float* ip = in + ((size_t)b*512 + c0)*HWSZ + s0;
  for (int i = ty; i < 64; i += 8) tile[i][tx] = ip[(size_t)i*HWSZ + tx];
  __syncthreads();
  for (int i = ty; i < 32; i += 8){
    unsigned lo = (unsigned)(unsigned short)f2b(tile[2*tx][i]);
    unsigned hi = (unsigned)(unsigned short)f2b(tile[2*tx+1][i]);
    unsigned pk = lo | (hi<<16);
    *reinterpret_cast<unsigned*>(&out[((size_t)((b<<12) + s0 + i))*512 + c0 + 2*tx]) = pk;
  }
}

// ---------------- bf16 MFMA GEMM: asymmetric pipeline (A 3-buf dist-2, W 2-buf dist-1) -------
// (R8 engine — best measured: 437 TF on merged GEMM)
template<int ACT, int OUT_NCHW>
__global__ __launch_bounds__(256) void k_gemm(
    const short* __restrict__ A0, const short* __restrict__ A1,
    int kSplit, int lda0, int lda1,
    const short* __restrict__ Wt, const float* __restrict__ bias,
    void* __restrict__ Cpv, int N, int K, int ldc, int qkvPerm,
    short* __restrict__ Cp2, int nSplit2, int ldc2)
{
  __shared__ short Alds[3][128*32];   // 24 KB, linear 64B rows
  __shared__ short Wlds[2][128*32];   // 16 KB

  int tid = threadIdx.x;
  int lane = tid & 63;
  int wv = tid >> 6;
  int wr = wv >> 1, wc = wv & 1;
  int lr = lane & 15, lh = lane >> 4;
  int bm = blockIdx.x * 128;
  int bn = blockIdx.y * 128;

  int rl = lane >> 2;        // row within a 16-row staging chunk
  int kg = (lane & 3) << 3;  // k element offset 0/8/16/24

  int ar[2], wnr[2];
  #pragma unroll
  for (int j=0;j<2;j++){
    int r = wv*32 + j*16 + rl;
    ar[j] = bm + r;
    int n = bn + r; if (n > N-1) n = N-1;   // clamp; garbage cols >=N discarded at epilogue
    wnr[j] = qkvPerm ? ((n==512)?0:(n+1)) : n;
  }

  auto stage_a = [&](int buf, int t){
    int k0 = t << 5;
    #pragma unroll
    for (int j=0;j<2;j++){
      const short* asrc;
      if (k0 < kSplit) asrc = A0 + (size_t)ar[j]*lda0 + (k0 + kg);
      else             asrc = A1 + (size_t)ar[j]*lda1 + (k0 - kSplit + kg);
      gload16(asrc, &Alds[buf][(wv*32 + j*16)*32]);
    }
  };
  auto stage_w = [&](int buf, int t){
    int k0 = t << 5;
    #pragma unroll
    for (int j=0;j<2;j++){
      const short* bsrc = Wt + (size_t)wnr[j]*K + (k0 + kg);
      gload16(bsrc, &Wlds[buf][(wv*32 + j*16)*32]);
    }
  };

  f32x4 acc[4][4];
  #pragma unroll
  for (int i=0;i<4;i++)
    #pragma unroll
    for (int j=0;j<4;j++) acc[i][j] = (f32x4){0.f,0.f,0.f,0.f};

  int NT = K >> 5;           // >= 8 for all our shapes
  // prologue issue order: W(0), A(0), A(1)  -> 6 loads/lane outstanding
  stage_w(0, 0);
  __builtin_amdgcn_sched_barrier(0);
  stage_a(0, 0);
  __builtin_amdgcn_sched_barrier(0);
  stage_a(1, 1);
  for (int t=0; t<NT; t++){
    int ab = t % 3, wb = t & 1;
    // entry in-flight (oldest->newest): A(t),W(t) [4] then A(t+1) [2]
    if (t+1 < NT) asm volatile("s_waitcnt vmcnt(2)" ::: "memory");
    else          asm volatile("s_waitcnt vmcnt(0)" ::: "memory");
    __builtin_amdgcn_s_barrier();
    __builtin_amdgcn_sched_barrier(0);
    if (t+1 < NT) stage_w(wb^1, t+1);
    __builtin_amdgcn_sched_barrier(0);
    if (t+2 < NT) stage_a((t+2)%3, t+2);
    __builtin_amdgcn_sched_barrier(0);
    bf16x8 af[4], bfr[4];
    #pragma unroll
    for (int mi=0;mi<4;mi++)
      af[mi] = *reinterpret_cast<const bf16x8*>(&Alds[ab][(wr*64 + mi*16 + lr)*32 + lh*8]);
    #pragma unroll
    for (int ni=0;ni<4;ni++)
      bfr[ni] = *reinterpret_cast<const bf16x8*>(&Wlds[wb][(wc*64 + ni*16 + lr)*32 + lh*8]);
    #pragma unroll
    for (int mi=0;mi<4;mi++)
      #pragma unroll
      for (int ni=0;ni<4;ni++)
        acc[mi][ni] = __builtin_amdgcn_mfma_f32_16x16x32_bf16(af[mi], bfr[ni], acc[mi][ni], 0, 0, 0);
  }

  if (!OUT_NCHW){
    short* Cp = (short*)Cpv;
    #pragma unroll
    for (int mi=0;mi<4;mi++){
      int m = bm + wr*64 + mi*16 + lh*4;
      #pragma unroll
      for (int ni=0;ni<4;ni++){
        int n = bn + wc*64 + ni*16 + lr;
        if (n < N){
          int wn = qkvPerm ? ((n==512)?0:(n+1)) : n;
          float bb = bias ? bias[wn] : 0.f;
          #pragma unroll
          for (int r=0;r<4;r++){
            float v = acc[mi][ni][r] + bb;
            if (ACT==1) v = siluf(v);
            short sv = f2b(v);
            if (n < nSplit2) Cp[(size_t)(m+r)*ldc + n] = sv;
            else             Cp2[(size_t)(m+r)*ldc2 + (n - nSplit2)] = sv;
          }
        }
      }
    }
  } else {
    // bulk transpose per wave through dead Alds: [16 m][64 n] f32, stride 68
    float* Cp = (float*)Cpv;
    float* Sep = ((float*)Alds) + wv*16*68;
    #pragma unroll
    for (int mi=0;mi<4;mi++){
      __syncthreads();
      #pragma unroll
      for (int ni=0;ni<4;ni++){
        int n = bn + wc*64 + ni*16 + lr;
        float bb = (bias && n < N) ? bias[n] : 0.f;
        #pragma unroll
        for (int r=0;r<4;r++){
          float v = acc[mi][ni][r] + bb;
          if (ACT==1) v = siluf(v);
          Sep[(lh*4+r)*68 + ni*16 + lr] = v;
        }
      }
      __syncthreads();
      int m = bm + wr*64 + mi*16 + lr;
      size_t mb = ((size_t)(m>>12)*ldc)*HWSZ + (m & 4095);
      #pragma unroll
      for (int g=0; g<16; g++){
        int nl = g*4 + lh;
        float v = Sep[lr*68 + nl];
        int nn = bn + wc*64 + nl;
        if (nn < N) Cp[mb + (size_t)nn*HWSZ] = v;
      }
    }
  }
}

// ---------------- depthwise 3x3 SAME + silu, pixel-major bf16 [P][512] ----------------
__global__ __launch_bounds__(256) void k_dwconv3x3(const short* __restrict__ in,
    const float* __restrict__ w, const float* __restrict__ bias, short* __restrict__ out){
  int tid = threadIdx.x;
  int cq = tid & 127;
  int wi = tid >> 7;
  int bw = blockIdx.x;              // b*32 + wpair
  int b  = bw >> 5;
  int wc = ((bw & 31) << 1) | wi;   // 0..63
  int h0 = blockIdx.y << 4;
  int c  = cq << 2;

  float arr[36];
  {
    const float* wp = &w[c*9];
    #pragma unroll
    for (int t=0;t<9;t++){
      f32x4 v = *reinterpret_cast<const f32x4*>(wp + t*4);
      arr[t*4+0]=v[0]; arr[t*4+1]=v[1]; arr[t*4+2]=v[2]; arr[t*4+3]=v[3];
    }
  }
  f32x4 bias4 = *reinterpret_cast<const f32x4*>(&bias[c]);

  int pb = b << 12;
  auto ldrow = [&](int r, int dw)->f32x4 {
    int ww = wc + dw;
    if ((unsigned)r >= 64u || (unsigned)ww >= 64u) return (f32x4){0.f,0.f,0.f,0.f};
    s16x4 v = *reinterpret_cast<const s16x4*>(&in[((size_t)(pb + (r<<6) + ww) << 9) + c]);
    return (f32x4){b2f(v[0]), b2f(v[1]), b2f(v[2]), b2f(v[3])};
  };

  f32x4 a00,a01,a02,a10,a11,a12,a20,a21,a22;
  a00=ldrow(h0-1,-1); a01=ldrow(h0-1,0); a02=ldrow(h0-1,1);
  a10=ldrow(h0  ,-1); a11=ldrow(h0  ,0); a12=ldrow(h0  ,1);
  #pragma unroll
  for (int hh=0; hh<16; hh++){
    int h = h0 + hh;
    a20=ldrow(h+1,-1); a21=ldrow(h+1,0); a22=ldrow(h+1,1);
    s16x4 o;
    #pragma unroll
    for (int j=0;j<4;j++){
      float v = bias4[j];
      v = fmaf(a00[j], arr[j*9+0], v);
      v = fmaf(a01[j], arr[j*9+1], v);
      v = fmaf(a02[j], arr[j*9+2], v);
      v = fmaf(a10[j], arr[j*9+3], v);
      v = fmaf(a11[j], arr[j*9+4], v);
      v = fmaf(a12[j], arr[j*9+5], v);
      v = fmaf(a20[j], arr[j*9+6], v);
      v = fmaf(a21[j], arr[j*9+7], v);
      v = fmaf(a22[j], arr[j*9+8], v);
      o[j] = f2b(siluf(v));
    }
    *reinterpret_cast<s16x4*>(&out[((size_t)(pb + (h<<6) + wc) << 9) + c]) = o;
    a00=a10; a01=a11; a02=a12;
    a10=a20; a11=a21; a12=a22;
  }
}

// ---------------- axis attention: layout k@0, v@+256, q@+512 within qkv (stride qld) --------
__global__ __launch_bounds__(256) void k_attn(const short* __restrict__ x, int xld,
    const short* __restrict__ qkv, int qld, short* __restrict__ out, int axisH){
  int bl = blockIdx.x;          // 0..511
  int b = bl >> 6, line = bl & 63;
  __shared__ float es[64];
  __shared__ float qs[64];
  int tid = threadIdx.x;
  int pbase = b << 12;
  if (tid < 64){
    int p = axisH ? (pbase | (tid<<6) | line) : (pbase | (line<<6) | tid);
    qs[tid] = b2f(qkv[(size_t)p*qld + 512]);
  }
  __syncthreads();
  float mx = -1e30f;
  for (int t=0;t<64;t++) mx = fmaxf(mx, qs[t]);
  if (tid < 64) es[tid] = __expf(qs[tid]-mx);
  __syncthreads();
  float s = 0.f;
  for (int t=0;t<64;t++) s += es[t];
  float inv = 1.f/s;
  int c = tid;                 // 256 channels
  float ctx = 0.f;
  for (int t=0;t<64;t++){
    int p = axisH ? (pbase | (t<<6) | line) : (pbase | (line<<6) | t);
    ctx += es[t]*b2f(qkv[(size_t)p*qld + c]);
  }
  ctx *= inv;
  for (int t=0;t<64;t++){
    int p = axisH ? (pbase | (t<<6) | line) : (pbase | (line<<6) | t);
    float vv = b2f(qkv[(size_t)p*qld + 256 + c]);
    float xv = b2f(x[(size_t)p*xld + c]);
    out[(size_t)p*256 + c] = f2b(xv + sigf(vv)*ctx);
  }
}

// ---------------- dt = softplus(xbcdt[:,512:514] + dt_bias) ----------------
__global__ __launch_bounds__(256) void k_dt(const short* __restrict__ xbcdt,
    const float* __restrict__ dt_bias, float* __restrict__ dtb){
  int idx = blockIdx.x*256 + threadIdx.x;   // P*2
  if (idx >= PTOT*2) return;
  int p = idx >> 1, h = idx & 1;
  float xv = b2f(xbcdt[(size_t)p*520 + 512 + h]) + dt_bias[h];
  float sp = (xv > 20.f) ? xv : log1pf(__expf(xv));
  dtb[idx] = sp;
}

// ---------------- causal depthwise conv1d (k=4) + silu, bf16 ----------------
__global__ __launch_bounds__(256) void k_conv1d(const short* __restrict__ xbcdt,
    const float* __restrict__ w, const float* __restrict__ bias, short* __restrict__ xBC){
  int tid = threadIdx.x;
  int cq = tid & 127;
  int c  = cq << 2;
  int half = tid >> 7;
  int bs = blockIdx.x;              // b*128 + strip-pair
  int b  = bs >> 7;
  int t0 = ((((bs & 127) << 1) | half) << 4);

  float wk[16];
  {
    const float* wp = &w[c*4];
    #pragma unroll
    for (int t=0;t<4;t++){
      f32x4 v = *reinterpret_cast<const f32x4*>(wp + t*4);
      wk[t*4+0]=v[0]; wk[t*4+1]=v[1]; wk[t*4+2]=v[2]; wk[t*4+3]=v[3];
    }
  }
  f32x4 bias4 = *reinterpret_cast<const f32x4*>(&bias[c]);

  int pb = b << 12;
  auto ld = [&](int t)->f32x4 {
    if (t < 0) return (f32x4){0.f,0.f,0.f,0.f};
    s16x4 v = *reinterpret_cast<const s16x4*>(&xbcdt[(size_t)(pb + t)*520 + c]);
    return (f32x4){b2f(v[0]), b2f(v[1]), b2f(v[2]), b2f(v[3])};
  };

  f32x4 x0,x1,x2,x3;
  x0 = ld(t0-3); x1 = ld(t0-2); x2 = ld(t0-1);
  #pragma unroll
  for (int tt=0; tt<16; tt++){
    int t = t0 + tt;
    x3 = ld(t);
    s16x4 o;
    #pragma unroll
    for (int j=0;j<4;j++){
      float v = bias4[j];
      v = fmaf(x0[j], wk[j*4+0], v);
      v = fmaf(x1[j], wk[j*4+1], v);
      v = fmaf(x2[j], wk[j*4+2], v);
      v = fmaf(x3[j], wk[j*4+3], v);
      o[j] = f2b(siluf(v));
    }
    *reinterpret_cast<s16x4*>(&xBC[((size_t)(pb + t) << 9) + c]) = o;
    x0=x1; x1=x2; x2=x3;
  }
}

// ---------------- SSD states (bf16 MFMA): cumsum + states[64n x 128p] = (B·d)^T @ (X·dt) -----
__global__ __launch_bounds__(256) void k_ssd_states(
  const short* __restrict__ xBC, const float* __restrict__ dtb, const float* __restrict__ A_log,
  float* __restrict__ states, float* __restrict__ AcsG, float* __restrict__ AtotG)
{
  int ci = blockIdx.x, h = blockIdx.y, b = blockIdx.z;
  int tid = threadIdx.x, lane = tid & 63, wv = tid >> 6;
  int lg = lane >> 4, lr = lane & 15;
  __shared__ float sa[256], sb[256];
  __shared__ short Bt[64*72];    // [n][t-chunk], stride 72 (144B -> 2-way alias)
  __shared__ short Xt[128*72];   // [p][t-chunk]
  int base = (b<<12) | (ci<<8);
  float Ah = -__expf(A_log[h]);
  sa[tid] = dtb[(size_t)(base + tid)*2 + h] * Ah;
  __syncthreads();
  float* src = sa; float* dst = sb;
  for (int off=1; off<256; off<<=1){
    float v = src[tid];
    if (tid >= off) v += src[tid - off];
    dst[tid] = v;
    __syncthreads();
    float* tswap = src; src = dst; dst = tswap;
  }
  float acs = src[tid];
  float atot = src[255];
  AcsG[((size_t)((b*2+h)*16 + ci))*256 + tid] = acs;
  if (tid == 0) AtotG[(b*2+h)*16 + ci] = atot;

  f32x4 acc[8];
  #pragma unroll
  for (int pf=0;pf<8;pf++) acc[pf] = (f32x4){0.f,0.f,0.f,0.f};

  for (int t0=0; t0<256; t0+=64){
    __syncthreads();
    // stage Bt[n][t] = B[t][n] * exp(atot - acs[t])   (bf16)
    {
      int t = tid >> 2;
      int n0 = (tid & 3) << 4;
      float d = __expf(atot - src[t0 + t]);
      const short* sp = &xBC[(size_t)(base + t0 + t)*512 + 256 + (h<<6) + n0];
      bf16x8 v0 = *reinterpret_cast<const bf16x8*>(sp);
      bf16x8 v1 = *reinterpret_cast<const bf16x8*>(sp+8);
      #pragma unroll
      for (int e=0;e<8;e++) Bt[(n0+e)*72 + t]   = f2b(b2f(v0[e])*d);
      #pragma unroll
      for (int e=0;e<8;e++) Bt[(n0+8+e)*72 + t] = f2b(b2f(v1[e])*d);
    }
    // stage Xt[p][t] = X[t][p] * dt[t]   (bf16)
    {
      int t = tid >> 2;
      int p0 = (tid & 3) << 5;
      float dtv = dtb[(size_t)(base + t0 + t)*2 + h];
      const short* sp = &xBC[(size_t)(base + t0 + t)*512 + (h<<7) + p0];
      #pragma unroll
      for (int q=0;q<4;q++){
        bf16x8 v = *reinterpret_cast<const bf16x8*>(sp + q*8);
        #pragma unroll
        for (int e=0;e<8;e++) Xt[(p0 + q*8 + e)*72 + t] = f2b(b2f(v[e])*dtv);
      }
    }
    __syncthreads();
    #pragma unroll
    for (int kk=0; kk<2; kk++){
      bf16x8 af = *reinterpret_cast<const bf16x8*>(&Bt[(wv*16 + lr)*72 + kk*32 + lg*8]);
      #pragma unroll
      for (int pf=0;pf<8;pf++){
        bf16x8 xf = *reinterpret_cast<const bf16x8*>(&Xt[(pf*16 + lr)*72 + kk*32 + lg*8]);
        acc[pf] = __builtin_amdgcn_mfma_f32_16x16x32_bf16(af, xf, acc[pf], 0, 0, 0);
      }
    }
  }
  // D layout: col(p)=lane&15, row(n)=(lane>>4)*4+r
  float* stp = states + (((size_t)(b*16+ci)*2 + h) << 13);
  #pragma unroll
  for (int pf=0;pf<8;pf++){
    #pragma unroll
    for (int r=0;r<4;r++)
      stp[(wv*16 + lg*4 + r)*128 + pf*16 + lr] = acc[pf][r];
  }
}

// ---------------- inter-chunk scan ----------------
__global__ __launch_bounds__(256) void k_ssd_scan(const float* __restrict__ states,
    const float* __restrict__ AtotG, float* __restrict__ R){
  int bh = blockIdx.x;   // b*2+h
  int b = bh >> 1, h = bh & 1;
  int tid = threadIdx.x;
  float r[32];
  #pragma unroll
  for (int j=0;j<32;j++) r[j]=0.f;
  for (int ci=0; ci<16; ci++){
    size_t off = (((size_t)(b*16+ci)*2) + h) << 13;
    #pragma unroll
    for (int j=0;j<32;j++) R[off + tid + (j<<8)] = r[j];
    if (ci < 15){
      float sc = __expf(AtotG[bh*16 + ci]);
      #pragma unroll
      for (int j=0;j<32;j++) r[j] = fmaf(sc, r[j], states[off + tid + (j<<8)]);
    }
  }
}

// ---------------- SSD Y (bf16 MFMA) ----------------
__global__ __launch_bounds__(256) void k_ssd_y(
  const short* __restrict__ xBC, const float* __restrict__ dtb,
  const float* __restrict__ AcsG, const float* __restrict__ R,
  const float* __restrict__ Dp, float* __restrict__ yraw)
{
  int bx = blockIdx.x;
  int ci = bx >> 2, lt = bx & 3;
  int h = blockIdx.y, b = blockIdx.z;
  int tid = threadIdx.x, lane = tid & 63, w = tid >> 6;
  int lg = lane >> 4, lr = lane & 15;
  int base = (b<<12) | (ci<<8);
  int l0 = lt << 6;

  __shared__ short Cbf[64*72];   // [l][n]  stride 72 bf16 (144B)
  __shared__ short Bbf[64*72];   // [s][n]
  __shared__ short Xt [128*76];  // [p][s] transposed, stride 76; reused for R^T [p][n]
  __shared__ short Sbf[64*72];   // [l][s]
  __shared__ float acs_l[64], acs_s[64], dt_s[64];

  const float* acsrow = AcsG + ((size_t)((b*2+h)*16 + ci))*256;

  // ---- stage C: 64 l-rows x 64 n (pure copy)
  {
    int row = tid >> 2, c0 = (tid & 3) << 4;
    const short* src = &xBC[(size_t)(base + l0 + row)*512 + 384 + (h<<6) + c0];
    *reinterpret_cast<bf16x8*>(&Cbf[row*72 + c0])     = *reinterpret_cast<const bf16x8*>(src);
    *reinterpret_cast<bf16x8*>(&Cbf[row*72 + c0 + 8]) = *reinterpret_cast<const bf16x8*>(src+8);
  }
  if (tid < 64) acs_l[tid] = acsrow[l0 + tid];

  f32x4 yacc[8];
  #pragma unroll
  for (int pf=0;pf<8;pf++) yacc[pf] = (f32x4){0.f,0.f,0.f,0.f};

  for (int s0 = 0; s0 <= l0; s0 += 64){
    __syncthreads();   // prev-iter readers done before restaging Bbf/Xt
    // ---- stage B (pure copy)
    {
      int row = tid >> 2, c0 = (tid & 3) << 4;
      const short* src = &xBC[(size_t)(base + s0 + row)*512 + 256 + (h<<6) + c0];
      *reinterpret_cast<bf16x8*>(&Bbf[row*72 + c0])     = *reinterpret_cast<const bf16x8*>(src);
      *reinterpret_cast<bf16x8*>(&Bbf[row*72 + c0 + 8]) = *reinterpret_cast<const bf16x8*>(src+8);
    }
    // ---- stage X transposed: Xt[p][s]
    {
      int s = tid >> 2;
      int p0 = (tid & 3) << 5;
      const short* src = &xBC[(size_t)(base + s0 + s)*512 + (h<<7) + p0];
      #pragma unroll
      for (int q=0;q<4;q++){
        bf16x8 v = *reinterpret_cast<const bf16x8*>(src + q*8);
        #pragma unroll
        for (int e=0;e<8;e++) Xt[(p0 + q*8 + e)*76 + s] = v[e];
      }
    }
    if (tid < 64){
      acs_s[tid] = acsrow[s0 + tid];
      dt_s[tid]  = dtb[(size_t)(base + s0 + tid)*2 + h];
    }
    __syncthreads();

    // ---- scores: sacc[f] = C(wave's 16 l) x B^T (64 s), K=n=64
    f32x4 sacc[4];
    #pragma unroll
    for (int f=0;f<4;f++) sacc[f] = (f32x4){0.f,0.f,0.f,0.f};
    bf16x8 ca0 = *reinterpret_cast<const bf16x8*>(&Cbf[(w*16+lr)*72 + lg*8]);
    bf16x8 ca1 = *reinterpret_cast<const bf16x8*>(&Cbf[(w*16+lr)*72 + 32 + lg*8]);
    #pragma unroll
    for (int f=0;f<4;f++){
      bf16x8 bb0 = *reinterpret_cast<const bf16x8*>(&Bbf[(f*16+lr)*72 + lg*8]);
      bf16x8 bb1 = *reinterpret_cast<const bf16x8*>(&Bbf[(f*16+lr)*72 + 32 + lg*8]);
      sacc[f] = __builtin_amdgcn_mfma_f32_16x16x32_bf16(ca0, bb0, sacc[f], 0, 0, 0);
      sacc[f] = __builtin_amdgcn_mfma_f32_16x16x32_bf16(ca1, bb1, sacc[f], 0, 0, 0);
    }
    // ---- mask * decay * dt -> Sbf[l][s] (bf16)
    #pragma unroll
    for (int f=0;f<4;f++){
      #pragma unroll
      for (int r=0;r<4;r++){
        int ll = w*16 + lg*4 + r;
        int ss = f*16 + lr;
        float v = 0.f;
        if (s0 + ss <= l0 + ll)
          v = sacc[f][r] * __expf(acs_l[ll] - acs_s[ss]) * dt_s[ss];
        Sbf[ll*72 + ss] = f2b(v);
      }
    }
    __syncthreads();

    // ---- Y += S' @ Xraw
    bf16x8 sa0 = *reinterpret_cast<const bf16x8*>(&Sbf[(w*16+lr)*72 + lg*8]);
    bf16x8 sa1 = *reinterpret_cast<const bf16x8*>(&Sbf[(w*16+lr)*72 + 32 + lg*8]);
    #pragma unroll
    for (int pf=0;pf<8;pf++){
      bf16x8 x0 = *reinterpret_cast<const bf16x8*>(&Xt[(pf*16+lr)*76 + lg*8]);
      bf16x8 x1 = *reinterpret_cast<const bf16x8*>(&Xt[(pf*16+lr)*76 + 32 + lg*8]);
      yacc[pf] = __builtin_amdgcn_mfma_f32_16x16x32_bf16(sa0, x0, yacc[pf], 0, 0, 0);
      yacc[pf] = __builtin_amdgcn_mfma_f32_16x16x32_bf16(sa1, x1, yacc[pf], 0, 0, 0);
    }
  }

  // ---- R term: restage Xt <- R^T  (R is f32 [n=64][p=128])
  __syncthreads();
  {
    size_t roff = (((size_t)(b*16+ci)*2) + h) << 13;
    int n = tid >> 2;
    const float* src = R + roff + (size_t)n*128;
    #pragma unroll
    for (int j=0;j<8;j++){
      int p = ((tid & 3) << 2) + (j << 4);
      float4 f = *reinterpret_cast<const float4*>(&src[p]);
      Xt[(p+0)*76 + n] = f2b(f.x);
      Xt[(p+1)*76 + n] = f2b(f.y);
      Xt[(p+2)*76 + n] = f2b(f.z);
      Xt[(p+3)*76 + n] = f2b(f.w);
    }
  }
  __syncthreads();
  f32x4 racc[8];
  #pragma unroll
  for (int pf=0;pf<8;pf++) racc[pf] = (f32x4){0.f,0.f,0.f,0.f};
  {
    bf16x8 ca0 = *reinterpret_cast<const bf16x8*>(&Cbf[(w*16+lr)*72 + lg*8]);
    bf16x8 ca1 = *reinterpret_cast<const bf16x8*>(&Cbf[(w*16+lr)*72 + 32 + lg*8]);
    #pragma unroll
    for (int pf=0;pf<8;pf++){
      bf16x8 x0 = *reinterpret_cast<const bf16x8*>(&Xt[(pf*16+lr)*76 + lg*8]);
      bf16x8 x1 = *reinterpret_cast<const bf16x8*>(&Xt[(pf*16+lr)*76 + 32 + lg*8]);
      racc[pf] = __builtin_amdgcn_mfma_f32_16x16x32_bf16(ca0, x0, racc[pf], 0, 0, 0);
      racc[pf] = __builtin_amdgcn_mfma_f32_16x16x32_bf16(ca1, x1, racc[pf], 0, 0, 0);
    }
  }

  // ---- epilogue: y = yacc + exp(acs_l)*racc + D*Xraw
  float Dh = Dp[h];
  float el[4];
  #pragma unroll
  for (int r=0;r<4;r++) el[r] = __expf(acs_l[w*16 + lg*4 + r]);
  #pragma unroll
  for (int pf=0;pf<8;pf++){
    #pragma unroll
    for (int r=0;r<4;r++){
      int ll = w*16 + lg*4 + r;
      int p = pf*16 + lr;
      size_t pix = (size_t)(base + l0 + ll);
      float xraw = b2f(xBC[pix*512 + (h<<7) + p]);
      yraw[pix*256 + (h<<7) + p] = yacc[pf][r] + el[r]*racc[pf][r] + Dh*xraw;
    }
  }
}

// ---------------- RMSNorm: wave-per-pixel, 4 pixels/block ----------------
__global__ __launch_bounds__(256) void k_rmsnorm(const float* __restrict__ yraw,
    const float* __restrict__ nw, short* __restrict__ ynorm){
  int tid = threadIdx.x, lane = tid & 63, wv = tid >> 6;
  int p = blockIdx.x*4 + wv;
  f32x4 v = *reinterpret_cast<const f32x4*>(&yraw[(size_t)p*256 + lane*4]);
  float sq = v[0]*v[0] + v[1]*v[1] + v[2]*v[2] + v[3]*v[3];
  #pragma unroll
  for (int off=32; off; off>>=1) sq += __shfl_down(sq, off);
  sq = __shfl(sq, 0);
  float scale = rsqrtf(sq*(1.f/256.f) + 1e-5f);
  f32x4 w4 = *reinterpret_cast<const f32x4*>(&nw[lane*4]);
  s16x4 o;
  #pragma unroll
  for (int j=0;j<4;j++) o[j] = f2b(v[j]*scale*w4[j]);
  *reinterpret_cast<s16x4*>(&ynorm[(size_t)p*256 + lane*4]) = o;
}

// =====================================================================================
extern "C" void kernel_launch(void* const* d_in, const int* in_sizes, int n_in,
                              void* d_out, int out_size, void* d_ws, size_t ws_size,
                              hipStream_t stream)
{
  (void)in_sizes; (void)n_in; (void)out_size; (void)ws_size;
  const float* u        = (const float*)d_in[0];
  const float* sc_w1    = (const float*)d_in[1];
  const float* sc_b1    = (const float*)d_in[2];
  const float* sc_wdw   = (const float*)d_in[3];
  const float* sc_bdw   = (const float*)d_in[4];
  const float* sc_w2    = (const float*)d_in[5];
  const float* sc_b2    = (const float*)d_in[6];
  const float* mc_w     = (const float*)d_in[7];
  const float* mc_b     = (const float*)d_in[8];
  const float* qkvW_w   = (const float*)d_in[9];
  const float* qkvW_b   = (const float*)d_in[10];
  const float* qkvH_w   = (const float*)d_in[11];
  const float* qkvH_b   = (const float*)d_in[12];
  const float* fuseW_w  = (const float*)d_in[13];
  const float* fuseW_b  = (const float*)d_in[14];
  const float* fuseH_w  = (const float*)d_in[15];
  const float* fuseH_b  = (const float*)d_in[16];
  const float* in_proj_w= (const float*)d_in[17];
  const float* conv1d_w = (const float*)d_in[18];
  const float* conv1d_b = (const float*)d_in[19];
  const float* dt_bias  = (const float*)d_in[20];
  const float* A_log    = (const float*)d_in[21];
  const float* Dp       = (const float*)d_in[22];
  const float* norm_w   = (const float*)d_in[23];
  const float* outp_w   = (const float*)d_in[24];
  const float* outp_b   = (const float*)d_in[25];

  char* wsb = (char*)d_ws;
  size_t off = 0;
  auto alloc = [&](size_t bytes){ void* p = wsb + off; off = (off + bytes + 255) & ~(size_t)255; return p; };
  short* wbf   = (short*)alloc((size_t)1246208*2);    // w_zx|w_sc2|w_qkvW|w_outp|wcomb|wi2
  float* bcomb = (float*)alloc(769*4);
  float* bi2   = (float*)alloc(514*4);
  float* bzx   = (float*)alloc(768*4);
  short* slotB = (short*)alloc((size_t)PTOT*776*2);   // z1(512) / qkvW(520) / merged(776) / xbcdt(520)
  short* slotC = (short*)alloc((size_t)PTOT*512*2);   // z1dw / xBC
  short* slotZ = (short*)alloc((size_t)PTOT*256*2);   // z
  short* slotE = (short*)alloc((size_t)PTOT*256*2);   // x1; later ynorm
  float* slotF = (float*)alloc((size_t)PTOT*256*4);   // xw/xh (bf16, front) ; later yraw (f32)
  float* slotS = (float*)alloc((size_t)4460000*4);    // SSD f32 scratch

  float* dtb     = slotS;                    // P*2      = 65536
  float* AcsG    = slotS + 65536;            // 65536
  float* AtotG   = slotS + 131072;           // 256
  float* statesB = slotS + 131328;           // 2097152
  float* Rb      = slotS + 131328 + 2097152; // 2097152
  short* ynorm   = slotE;
  short* xwh     = (short*)slotF;            // bf16 view for attn outputs

  // weight table (element offsets into wbf)
  short* w_zx   = wbf + 0;         // 768 x 512  [sc_w1 ; mc_w]
  short* w_sc2  = wbf + 393216;    // 256 x 512
  short* w_qkvW = wbf + 524288;    // 513 x 256
  short* w_outp = wbf + 655616;    // 512 x 512
  short* wcomb  = wbf + 917760;    // 769 x 256
  short* wi2    = wbf + 1114624;   // 514 x 256

  short* u_pm = (short*)d_out;  // d_out doubles as bf16 pixel-major u scratch (32MB of 64MB)
  float* out  = (float*)d_out;

  const int BIG = 1<<30;

  k_cvtw<<<3585, 256, 0, stream>>>(sc_w1, mc_w, sc_w2, qkvW_w, outp_w, wbf);
  k_wcomp<<<1286, 256, 0, stream>>>(qkvH_w, fuseW_w, fuseW_b, qkvH_b, in_proj_w, fuseH_w, fuseH_b,
                                    sc_b1, mc_b, wcomb, bcomb, wi2, bi2, bzx);
  k_transpose<<<dim3(128,8,8), dim3(32,8), 0, stream>>>(u, u_pm);

  // merged z1 + x1: N=768, dual output (z1 -> slotB ld512; x1 -> slotE ld256)
  k_gemm<1,0><<<dim3(256,6), 256, 0, stream>>>(u_pm, u_pm, BIG, 512, 512, w_zx, bzx,
                                               slotB, 768, 512, 512, 0, slotE, 512, 256);
  // z-branch
  k_dwconv3x3<<<dim3(256,4), 256, 0, stream>>>(slotB, sc_wdw, sc_bdw, slotC);
  k_gemm<1,0><<<dim3(256,2), 256, 0, stream>>>(slotC, slotC, BIG, 512, 512, w_sc2, sc_b2,
                                               slotZ, 256, 512, 256, 0, nullptr, BIG, 0);

  // x-branch: qkv W: [k|v|q] stride 520
  k_gemm<0,0><<<dim3(256,5), 256, 0, stream>>>(slotE, slotE, BIG, 256, 256, w_qkvW, qkvW_b,
                                               slotB, 513, 256, 520, 1, nullptr, BIG, 0);
  k_attn<<<512, 256, 0, stream>>>(slotE, 256, slotB, 520, xwh, 0);
  // merged fuseW + (qkvH∘fuseW): [a2(256) | k|v|q(513)] stride 776
  k_gemm<0,0><<<dim3(256,7), 256, 0, stream>>>(xwh, xwh, BIG, 256, 256, wcomb, bcomb,
                                               slotB, 769, 256, 776, 0, nullptr, BIG, 0);
  k_attn<<<512, 256, 0, stream>>>(slotB, 776, slotB + 256, 776, xwh, 1);
  // composed in_proj: xbcdt [xBC(512) | dt(2)] stride 520
  k_gemm<0,0><<<dim3(256,5), 256, 0, stream>>>(xwh, xwh, BIG, 256, 256, wi2, bi2,
                                               slotB, 514, 256, 520, 0, nullptr, BIG, 0);
  k_dt<<<256, 256, 0, stream>>>(slotB, dt_bias, dtb);
  k_conv1d<<<1024, 256, 0, stream>>>(slotB, conv1d_w, conv1d_b, slotC);

  // SSD
  k_ssd_states<<<dim3(16,2,8), 256, 0, stream>>>(slotC, dtb, A_log, statesB, AcsG, AtotG);
  k_ssd_scan<<<16, 256, 0, stream>>>(statesB, AtotG, Rb);
  k_ssd_y<<<dim3(64,2,8), 256, 0, stream>>>(slotC, dtb, AcsG, Rb, Dp, slotF);

  // RMSNorm (f32 yraw -> bf16 ynorm in slotE), wave-per-pixel
  k_rmsnorm<<<8192, 256, 0, stream>>>(slotF, norm_w, ynorm);

  // final: out = concat(z, ynorm) @ outp_w^T + b, written f32 NCHW into d_out
  k_gemm<0,1><<<dim3(256,4), 256, 0, stream>>>(slotZ, ynorm, 256, 256, 256, w_outp, outp_b,
                                               out, 512, 512, 512, 0, nullptr, BIG, 0);
}

// Round 11
// 409.133 us; speedup vs baseline: 1.2626x; 1.0663x over previous
//
#include <hip/hip_runtime.h>
#include <hip/hip_bf16.h>
#include <cstddef>
#include <cstdint>

#define PTOT 32768   // 8 * 64 * 64 pixels
#define HWSZ 4096

typedef __attribute__((ext_vector_type(8))) short bf16x8;
typedef __attribute__((ext_vector_type(4))) short s16x4;
typedef __attribute__((ext_vector_type(4))) float f32x4;

__device__ __forceinline__ float sigf(float x){ return 1.f/(1.f+__expf(-x)); }
__device__ __forceinline__ float siluf(float x){ return x*sigf(x); }
__device__ __forceinline__ short f2b(float x){
  __hip_bfloat16 h = __float2bfloat16(x);
  return *reinterpret_cast<short*>(&h);
}
__device__ __forceinline__ float b2f(short s){
  unsigned u = ((unsigned)(unsigned short)s) << 16;
  return __uint_as_float(u);
}

// async global->LDS, 16B per lane. LDS dest = wave-uniform base + lane*16.
__device__ __forceinline__ void gload16(const void* g, void* l){
  __builtin_amdgcn_global_load_lds(
      (const __attribute__((address_space(1))) unsigned int*)g,
      (__attribute__((address_space(3))) unsigned int*)l, 16, 0, 0);
}

// ---------------- weight conversion f32 -> bf16 ----------------
__global__ __launch_bounds__(256) void k_cvtw(
    const float* __restrict__ s0, const float* __restrict__ s1, const float* __restrict__ s2,
    const float* __restrict__ s3, const float* __restrict__ s4,
    short* __restrict__ dst){
  int idx = blockIdx.x*256 + threadIdx.x;
  const float* s; int off;
  if      (idx <  262144){ s=s0; off=idx; }
  else if (idx <  393216){ s=s1; off=idx- 262144; }
  else if (idx <  524288){ s=s2; off=idx- 393216; }
  else if (idx <  655616){ s=s3; off=idx- 524288; }
  else if (idx <  917760){ s=s4; off=idx- 655616; }
  else return;
  dst[idx] = f2b(s[off]);
}

// ---------------- weight composition (linear-linear fusion) + bias concat ----------------
__global__ __launch_bounds__(256) void k_wcomp(
    const float* __restrict__ qkvHw, const float* __restrict__ fuWw,
    const float* __restrict__ fuWb,  const float* __restrict__ qkvHb,
    const float* __restrict__ inpw,  const float* __restrict__ fuHw,
    const float* __restrict__ fuHb,
    const float* __restrict__ scb1,  const float* __restrict__ mcb,
    short* __restrict__ wcomb, float* __restrict__ bcomb,
    short* __restrict__ wi2,   float* __restrict__ bi2,
    float* __restrict__ bzx)
{
  int blk = blockIdx.x;
  int tid = threadIdx.x;
  __shared__ float as[256];
  __shared__ float red[256];
  if (blk < 513){
    int i = blk;
    int r = (i==512) ? 0 : (i+1);
    as[tid]  = qkvHw[(size_t)r*256 + tid];
    red[tid] = as[tid] * fuWb[tid];
    __syncthreads();
    for (int off=128; off; off>>=1){ if (tid<off) red[tid]+=red[tid+off]; __syncthreads(); }
    float acc = 0.f;
    #pragma unroll 8
    for (int k=0;k<256;k++) acc += as[k]*fuWw[(size_t)k*256 + tid];
    wcomb[(size_t)(256+i)*256 + tid] = f2b(acc);
    if (tid==0) bcomb[256+i] = red[0] + qkvHb[r];
  } else if (blk < 769){
    int j = blk - 513;
    wcomb[(size_t)j*256 + tid] = f2b(fuWw[(size_t)j*256 + tid]);
    if (tid==0) bcomb[j] = fuWb[j];
  } else if (blk < 1283){
    int j = blk - 769;   // 0..513
    as[tid]  = inpw[(size_t)j*256 + tid];
    red[tid] = as[tid] * fuHb[tid];
    __syncthreads();
    for (int off=128; off; off>>=1){ if (tid<off) red[tid]+=red[tid+off]; __syncthreads(); }
    float acc = 0.f;
    #pragma unroll 8
    for (int k=0;k<256;k++) acc += as[k]*fuHw[(size_t)k*256 + tid];
    wi2[(size_t)j*256 + tid] = f2b(acc);
    if (tid==0) bi2[j] = red[0];
  } else {
    int j = (blk - 1283)*256 + tid;   // 0..767
    bzx[j] = (j < 512) ? scb1[j] : mcb[j-512];
  }
}

// ---------------- NCHW f32 -> pixel-major bf16 transpose ----------------
__global__ __launch_bounds__(256) void k_transpose(const float* __restrict__ in, short* __restrict__ out){
  __shared__ float tile[64][33];
  int b = blockIdx.z;
  int c0 = blockIdx.y * 64;
  int s0 = blockIdx.x * 32;
  int tx = threadIdx.x, ty = threadIdx.y;
  const float* ip = in + ((size_t)b*512 + c0)*HWSZ + s0;
  for (int i = ty; i < 64; i += 8) tile[i][tx] = ip[(size_t)i*HWSZ + tx];
  __syncthreads();
  for (int i = ty; i < 32; i += 8){
    unsigned lo = (unsigned)(unsigned short)f2b(tile[2*tx][i]);
    unsigned hi = (unsigned)(unsigned short)f2b(tile[2*tx+1][i]);
    unsigned pk = lo | (hi<<16);
    *reinterpret_cast<unsigned*>(&out[((size_t)((b<<12) + s0 + i))*512 + c0 + 2*tx]) = pk;
  }
}

// ---------------- bf16 MFMA GEMM: asymmetric pipeline (A 3-buf dist-2, W 2-buf dist-1) -------
// (R8 engine — frozen; best measured 441 TF)
template<int ACT, int OUT_NCHW>
__global__ __launch_bounds__(256) void k_gemm(
    const short* __restrict__ A0, const short* __restrict__ A1,
    int kSplit, int lda0, int lda1,
    const short* __restrict__ Wt, const float* __restrict__ bias,
    void* __restrict__ Cpv, int N, int K, int ldc, int qkvPerm,
    short* __restrict__ Cp2, int nSplit2, int ldc2)
{
  __shared__ short Alds[3][128*32];   // 24 KB, linear 64B rows
  __shared__ short Wlds[2][128*32];   // 16 KB

  int tid = threadIdx.x;
  int lane = tid & 63;
  int wv = tid >> 6;
  int wr = wv >> 1, wc = wv & 1;
  int lr = lane & 15, lh = lane >> 4;
  int bm = blockIdx.x * 128;
  int bn = blockIdx.y * 128;

  int rl = lane >> 2;        // row within a 16-row staging chunk
  int kg = (lane & 3) << 3;  // k element offset 0/8/16/24

  int ar[2], wnr[2];
  #pragma unroll
  for (int j=0;j<2;j++){
    int r = wv*32 + j*16 + rl;
    ar[j] = bm + r;
    int n = bn + r; if (n > N-1) n = N-1;
    wnr[j] = qkvPerm ? ((n==512)?0:(n+1)) : n;
  }

  auto stage_a = [&](int buf, int t){
    int k0 = t << 5;
    #pragma unroll
    for (int j=0;j<2;j++){
      const short* asrc;
      if (k0 < kSplit) asrc = A0 + (size_t)ar[j]*lda0 + (k0 + kg);
      else             asrc = A1 + (size_t)ar[j]*lda1 + (k0 - kSplit + kg);
      gload16(asrc, &Alds[buf][(wv*32 + j*16)*32]);
    }
  };
  auto stage_w = [&](int buf, int t){
    int k0 = t << 5;
    #pragma unroll
    for (int j=0;j<2;j++){
      const short* bsrc = Wt + (size_t)wnr[j]*K + (k0 + kg);
      gload16(bsrc, &Wlds[buf][(wv*32 + j*16)*32]);
    }
  };

  f32x4 acc[4][4];
  #pragma unroll
  for (int i=0;i<4;i++)
    #pragma unroll
    for (int j=0;j<4;j++) acc[i][j] = (f32x4){0.f,0.f,0.f,0.f};

  int NT = K >> 5;
  stage_w(0, 0);
  __builtin_amdgcn_sched_barrier(0);
  stage_a(0, 0);
  __builtin_amdgcn_sched_barrier(0);
  stage_a(1, 1);
  for (int t=0; t<NT; t++){
    int ab = t % 3, wb = t & 1;
    if (t+1 < NT) asm volatile("s_waitcnt vmcnt(2)" ::: "memory");
    else          asm volatile("s_waitcnt vmcnt(0)" ::: "memory");
    __builtin_amdgcn_s_barrier();
    __builtin_amdgcn_sched_barrier(0);
    if (t+1 < NT) stage_w(wb^1, t+1);
    __builtin_amdgcn_sched_barrier(0);
    if (t+2 < NT) stage_a((t+2)%3, t+2);
    __builtin_amdgcn_sched_barrier(0);
    bf16x8 af[4], bfr[4];
    #pragma unroll
    for (int mi=0;mi<4;mi++)
      af[mi] = *reinterpret_cast<const bf16x8*>(&Alds[ab][(wr*64 + mi*16 + lr)*32 + lh*8]);
    #pragma unroll
    for (int ni=0;ni<4;ni++)
      bfr[ni] = *reinterpret_cast<const bf16x8*>(&Wlds[wb][(wc*64 + ni*16 + lr)*32 + lh*8]);
    #pragma unroll
    for (int mi=0;mi<4;mi++)
      #pragma unroll
      for (int ni=0;ni<4;ni++)
        acc[mi][ni] = __builtin_amdgcn_mfma_f32_16x16x32_bf16(af[mi], bfr[ni], acc[mi][ni], 0, 0, 0);
  }

  if (!OUT_NCHW){
    short* Cp = (short*)Cpv;
    #pragma unroll
    for (int mi=0;mi<4;mi++){
      int m = bm + wr*64 + mi*16 + lh*4;
      #pragma unroll
      for (int ni=0;ni<4;ni++){
        int n = bn + wc*64 + ni*16 + lr;
        if (n < N){
          int wn = qkvPerm ? ((n==512)?0:(n+1)) : n;
          float bb = bias ? bias[wn] : 0.f;
          #pragma unroll
          for (int r=0;r<4;r++){
            float v = acc[mi][ni][r] + bb;
            if (ACT==1) v = siluf(v);
            short sv = f2b(v);
            if (n < nSplit2) Cp[(size_t)(m+r)*ldc + n] = sv;
            else             Cp2[(size_t)(m+r)*ldc2 + (n - nSplit2)] = sv;
          }
        }
      }
    }
  } else {
    float* Cp = (float*)Cpv;
    float* Sep = ((float*)Alds) + wv*16*68;
    #pragma unroll
    for (int mi=0;mi<4;mi++){
      __syncthreads();
      #pragma unroll
      for (int ni=0;ni<4;ni++){
        int n = bn + wc*64 + ni*16 + lr;
        float bb = (bias && n < N) ? bias[n] : 0.f;
        #pragma unroll
        for (int r=0;r<4;r++){
          float v = acc[mi][ni][r] + bb;
          if (ACT==1) v = siluf(v);
          Sep[(lh*4+r)*68 + ni*16 + lr] = v;
        }
      }
      __syncthreads();
      int m = bm + wr*64 + mi*16 + lr;
      size_t mb = ((size_t)(m>>12)*ldc)*HWSZ + (m & 4095);
      #pragma unroll
      for (int g=0; g<16; g++){
        int nl = g*4 + lh;
        float v = Sep[lr*68 + nl];
        int nn = bn + wc*64 + nl;
        if (nn < N) Cp[mb + (size_t)nn*HWSZ] = v;
      }
    }
  }
}

// ---------------- depthwise 3x3 SAME + silu, pixel-major bf16 [P][512] ----------------
__global__ __launch_bounds__(256) void k_dwconv3x3(const short* __restrict__ in,
    const float* __restrict__ w, const float* __restrict__ bias, short* __restrict__ out){
  int tid = threadIdx.x;
  int cq = tid & 127;
  int wi = tid >> 7;
  int bw = blockIdx.x;              // b*32 + wpair
  int b  = bw >> 5;
  int wc = ((bw & 31) << 1) | wi;   // 0..63
  int h0 = blockIdx.y << 4;
  int c  = cq << 2;

  float arr[36];
  {
    const float* wp = &w[c*9];
    #pragma unroll
    for (int t=0;t<9;t++){
      f32x4 v = *reinterpret_cast<const f32x4*>(wp + t*4);
      arr[t*4+0]=v[0]; arr[t*4+1]=v[1]; arr[t*4+2]=v[2]; arr[t*4+3]=v[3];
    }
  }
  f32x4 bias4 = *reinterpret_cast<const f32x4*>(&bias[c]);

  int pb = b << 12;
  auto ldrow = [&](int r, int dw)->f32x4 {
    int ww = wc + dw;
    if ((unsigned)r >= 64u || (unsigned)ww >= 64u) return (f32x4){0.f,0.f,0.f,0.f};
    s16x4 v = *reinterpret_cast<const s16x4*>(&in[((size_t)(pb + (r<<6) + ww) << 9) + c]);
    return (f32x4){b2f(v[0]), b2f(v[1]), b2f(v[2]), b2f(v[3])};
  };

  f32x4 a00,a01,a02,a10,a11,a12,a20,a21,a22;
  a00=ldrow(h0-1,-1); a01=ldrow(h0-1,0); a02=ldrow(h0-1,1);
  a10=ldrow(h0  ,-1); a11=ldrow(h0  ,0); a12=ldrow(h0  ,1);
  #pragma unroll
  for (int hh=0; hh<16; hh++){
    int h = h0 + hh;
    a20=ldrow(h+1,-1); a21=ldrow(h+1,0); a22=ldrow(h+1,1);
    s16x4 o;
    #pragma unroll
    for (int j=0;j<4;j++){
      float v = bias4[j];
      v = fmaf(a00[j], arr[j*9+0], v);
      v = fmaf(a01[j], arr[j*9+1], v);
      v = fmaf(a02[j], arr[j*9+2], v);
      v = fmaf(a10[j], arr[j*9+3], v);
      v = fmaf(a11[j], arr[j*9+4], v);
      v = fmaf(a12[j], arr[j*9+5], v);
      v = fmaf(a20[j], arr[j*9+6], v);
      v = fmaf(a21[j], arr[j*9+7], v);
      v = fmaf(a22[j], arr[j*9+8], v);
      o[j] = f2b(siluf(v));
    }
    *reinterpret_cast<s16x4*>(&out[((size_t)(pb + (h<<6) + wc) << 9) + c]) = o;
    a00=a10; a01=a11; a02=a12;
    a10=a20; a11=a21; a12=a22;
  }
}

// ---------------- attn ctx: per (b,line), parallel over t: ctx[c] = softmax(q).k ------------
__global__ __launch_bounds__(256) void k_attn_ctx(const short* __restrict__ qkv, int qld,
    float* __restrict__ ctx, int axisH){
  int bl = blockIdx.x;          // b*64 + line
  int b = bl >> 6, line = bl & 63;
  int tid = threadIdx.x;
  int pbase = b << 12;
  __shared__ float qs[64], es[64];
  __shared__ float part[8][260];
  auto pos = [&](int t)->int { return axisH ? (pbase | (t<<6) | line) : (pbase | (line<<6) | t); };
  if (tid < 64) qs[tid] = b2f(qkv[(size_t)pos(tid)*qld + 512]);
  __syncthreads();
  float mx = -1e30f;
  for (int t=0;t<64;t++) mx = fmaxf(mx, qs[t]);
  if (tid < 64) es[tid] = __expf(qs[tid]-mx);
  __syncthreads();
  int tg = tid >> 5;            // 0..7 (t-groups of 8)
  int cg = tid & 31;            // 0..31 (channel-groups of 8)
  float pacc[8];
  #pragma unroll
  for (int j=0;j<8;j++) pacc[j]=0.f;
  #pragma unroll
  for (int tt=0; tt<8; tt++){
    int t = tg*8 + tt;
    bf16x8 kv = *reinterpret_cast<const bf16x8*>(&qkv[(size_t)pos(t)*qld + cg*8]);
    float e = es[t];
    #pragma unroll
    for (int j=0;j<8;j++) pacc[j] = fmaf(e, b2f(kv[j]), pacc[j]);
  }
  #pragma unroll
  for (int j=0;j<8;j++) part[tg][cg*8+j] = pacc[j];
  __syncthreads();
  float s = 0.f;
  for (int t=0;t<64;t++) s += es[t];
  float inv = 1.f/s;
  int c = tid;
  float v = 0.f;
  #pragma unroll
  for (int g=0; g<8; g++) v += part[g][c];
  ctx[(size_t)bl*256 + c] = v*inv;
}

// ---------------- attn apply: out = x + sigmoid(v)*ctx[line]  (elementwise, vectorized) -----
__global__ __launch_bounds__(256) void k_attn_apply(const short* __restrict__ x, int xld,
    const short* __restrict__ qkv, int qld, const float* __restrict__ ctx,
    short* __restrict__ out, int axisH){
  int idx = blockIdx.x*256 + threadIdx.x;   // P*32 work items, 8 channels each
  int p = idx >> 5;
  int c0 = (idx & 31) << 3;
  int line = axisH ? (p & 63) : ((p >> 6) & 63);
  int bl = (p >> 12)*64 + line;
  bf16x8 vv = *reinterpret_cast<const bf16x8*>(&qkv[(size_t)p*qld + 256 + c0]);
  bf16x8 xv = *reinterpret_cast<const bf16x8*>(&x[(size_t)p*xld + c0]);
  const float* cp = &ctx[(size_t)bl*256 + c0];
  bf16x8 o;
  #pragma unroll
  for (int j=0;j<8;j++)
    o[j] = f2b(b2f(xv[j]) + sigf(b2f(vv[j]))*cp[j]);
  *reinterpret_cast<bf16x8*>(&out[(size_t)p*256 + c0]) = o;
}

// ---------------- dt = softplus(xbcdt[:,512:514] + dt_bias) ----------------
__global__ __launch_bounds__(256) void k_dt(const short* __restrict__ xbcdt,
    const float* __restrict__ dt_bias, float* __restrict__ dtb){
  int idx = blockIdx.x*256 + threadIdx.x;   // P*2
  if (idx >= PTOT*2) return;
  int p = idx >> 1, h = idx & 1;
  float xv = b2f(xbcdt[(size_t)p*520 + 512 + h]) + dt_bias[h];
  float sp = (xv > 20.f) ? xv : log1pf(__expf(xv));
  dtb[idx] = sp;
}

// ---------------- causal depthwise conv1d (k=4) + silu, bf16 ----------------
__global__ __launch_bounds__(256) void k_conv1d(const short* __restrict__ xbcdt,
    const float* __restrict__ w, const float* __restrict__ bias, short* __restrict__ xBC){
  int tid = threadIdx.x;
  int cq = tid & 127;
  int c  = cq << 2;
  int half = tid >> 7;
  int bs = blockIdx.x;              // b*128 + strip-pair
  int b  = bs >> 7;
  int t0 = ((((bs & 127) << 1) | half) << 4);

  float wk[16];
  {
    const float* wp = &w[c*4];
    #pragma unroll
    for (int t=0;t<4;t++){
      f32x4 v = *reinterpret_cast<const f32x4*>(wp + t*4);
      wk[t*4+0]=v[0]; wk[t*4+1]=v[1]; wk[t*4+2]=v[2]; wk[t*4+3]=v[3];
    }
  }
  f32x4 bias4 = *reinterpret_cast<const f32x4*>(&bias[c]);

  int pb = b << 12;
  auto ld = [&](int t)->f32x4 {
    if (t < 0) return (f32x4){0.f,0.f,0.f,0.f};
    s16x4 v = *reinterpret_cast<const s16x4*>(&xbcdt[(size_t)(pb + t)*520 + c]);
    return (f32x4){b2f(v[0]), b2f(v[1]), b2f(v[2]), b2f(v[3])};
  };

  f32x4 x0,x1,x2,x3;
  x0 = ld(t0-3); x1 = ld(t0-2); x2 = ld(t0-1);
  #pragma unroll
  for (int tt=0; tt<16; tt++){
    int t = t0 + tt;
    x3 = ld(t);
    s16x4 o;
    #pragma unroll
    for (int j=0;j<4;j++){
      float v = bias4[j];
      v = fmaf(x0[j], wk[j*4+0], v);
      v = fmaf(x1[j], wk[j*4+1], v);
      v = fmaf(x2[j], wk[j*4+2], v);
      v = fmaf(x3[j], wk[j*4+3], v);
      o[j] = f2b(siluf(v));
    }
    *reinterpret_cast<s16x4*>(&xBC[((size_t)(pb + t) << 9) + c]) = o;
    x0=x1; x1=x2; x2=x3;
  }
}

// ---------------- SSD states (bf16 MFMA) ----------------
__global__ __launch_bounds__(256) void k_ssd_states(
  const short* __restrict__ xBC, const float* __restrict__ dtb, const float* __restrict__ A_log,
  float* __restrict__ states, float* __restrict__ AcsG, float* __restrict__ AtotG)
{
  int ci = blockIdx.x, h = blockIdx.y, b = blockIdx.z;
  int tid = threadIdx.x, lane = tid & 63, wv = tid >> 6;
  int lg = lane >> 4, lr = lane & 15;
  __shared__ float sa[256], sb[256];
  __shared__ short Bt[64*72];    // [n][t-chunk]
  __shared__ short Xt[128*72];   // [p][t-chunk]
  int base = (b<<12) | (ci<<8);
  float Ah = -__expf(A_log[h]);
  sa[tid] = dtb[(size_t)(base + tid)*2 + h] * Ah;
  __syncthreads();
  float* src = sa; float* dst = sb;
  for (int off=1; off<256; off<<=1){
    float v = src[tid];
    if (tid >= off) v += src[tid - off];
    dst[tid] = v;
    __syncthreads();
    float* tswap = src; src = dst; dst = tswap;
  }
  float acs = src[tid];
  float atot = src[255];
  AcsG[((size_t)((b*2+h)*16 + ci))*256 + tid] = acs;
  if (tid == 0) AtotG[(b*2+h)*16 + ci] = atot;

  f32x4 acc[8];
  #pragma unroll
  for (int pf=0;pf<8;pf++) acc[pf] = (f32x4){0.f,0.f,0.f,0.f};

  for (int t0=0; t0<256; t0+=64){
    __syncthreads();
    {
      int t = tid >> 2;
      int n0 = (tid & 3) << 4;
      float d = __expf(atot - src[t0 + t]);
      const short* sp = &xBC[(size_t)(base + t0 + t)*512 + 256 + (h<<6) + n0];
      bf16x8 v0 = *reinterpret_cast<const bf16x8*>(sp);
      bf16x8 v1 = *reinterpret_cast<const bf16x8*>(sp+8);
      #pragma unroll
      for (int e=0;e<8;e++) Bt[(n0+e)*72 + t]   = f2b(b2f(v0[e])*d);
      #pragma unroll
      for (int e=0;e<8;e++) Bt[(n0+8+e)*72 + t] = f2b(b2f(v1[e])*d);
    }
    {
      int t = tid >> 2;
      int p0 = (tid & 3) << 5;
      float dtv = dtb[(size_t)(base + t0 + t)*2 + h];
      const short* sp = &xBC[(size_t)(base + t0 + t)*512 + (h<<7) + p0];
      #pragma unroll
      for (int q=0;q<4;q++){
        bf16x8 v = *reinterpret_cast<const bf16x8*>(sp + q*8);
        #pragma unroll
        for (int e=0;e<8;e++) Xt[(p0 + q*8 + e)*72 + t] = f2b(b2f(v[e])*dtv);
      }
    }
    __syncthreads();
    #pragma unroll
    for (int kk=0; kk<2; kk++){
      bf16x8 af = *reinterpret_cast<const bf16x8*>(&Bt[(wv*16 + lr)*72 + kk*32 + lg*8]);
      #pragma unroll
      for (int pf=0;pf<8;pf++){
        bf16x8 xf = *reinterpret_cast<const bf16x8*>(&Xt[(pf*16 + lr)*72 + kk*32 + lg*8]);
        acc[pf] = __builtin_amdgcn_mfma_f32_16x16x32_bf16(af, xf, acc[pf], 0, 0, 0);
      }
    }
  }
  float* stp = states + (((size_t)(b*16+ci)*2 + h) << 13);
  #pragma unroll
  for (int pf=0;pf<8;pf++){
    #pragma unroll
    for (int r=0;r<4;r++)
      stp[(wv*16 + lg*4 + r)*128 + pf*16 + lr] = acc[pf][r];
  }
}

// ---------------- inter-chunk scan ----------------
__global__ __launch_bounds__(256) void k_ssd_scan(const float* __restrict__ states,
    const float* __restrict__ AtotG, float* __restrict__ R){
  int bh = blockIdx.x;   // b*2+h
  int b = bh >> 1, h = bh & 1;
  int tid = threadIdx.x;
  float r[32];
  #pragma unroll
  for (int j=0;j<32;j++) r[j]=0.f;
  for (int ci=0; ci<16; ci++){
    size_t off = (((size_t)(b*16+ci)*2) + h) << 13;
    #pragma unroll
    for (int j=0;j<32;j++) R[off + tid + (j<<8)] = r[j];
    if (ci < 15){
      float sc = __expf(AtotG[bh*16 + ci]);
      #pragma unroll
      for (int j=0;j<32;j++) r[j] = fmaf(sc, r[j], states[off + tid + (j<<8)]);
    }
  }
}

// ---------------- SSD Y + RMSNorm fused (both heads per block), bf16 out --------------------
__global__ __launch_bounds__(256) void k_ssd_y_norm(
  const short* __restrict__ xBC, const float* __restrict__ dtb,
  const float* __restrict__ AcsG, const float* __restrict__ R,
  const float* __restrict__ Dp, const float* __restrict__ nw, short* __restrict__ ynorm)
{
  int bx = blockIdx.x;
  int ci = bx >> 2, lt = bx & 3;
  int b = blockIdx.y;
  int tid = threadIdx.x, lane = tid & 63, w = tid >> 6;
  int lg = lane >> 4, lr = lane & 15;
  int base = (b<<12) | (ci<<8);
  int l0 = lt << 6;

  __shared__ short Cbf[64*72];
  __shared__ short Bbf[64*72];
  __shared__ short Xt [128*76];
  __shared__ short Sbf[64*72];
  __shared__ float acs_l[64], acs_s[64], dt_s[64];

  auto body = [&](int h, f32x4* yv){
    __syncthreads();   // prior head's readers done before restaging Cbf/acs_l
    const float* acsrow = AcsG + ((size_t)((b*2+h)*16 + ci))*256;
    {
      int row = tid >> 2, c0 = (tid & 3) << 4;
      const short* src = &xBC[(size_t)(base + l0 + row)*512 + 384 + (h<<6) + c0];
      *reinterpret_cast<bf16x8*>(&Cbf[row*72 + c0])     = *reinterpret_cast<const bf16x8*>(src);
      *reinterpret_cast<bf16x8*>(&Cbf[row*72 + c0 + 8]) = *reinterpret_cast<const bf16x8*>(src+8);
    }
    if (tid < 64) acs_l[tid] = acsrow[l0 + tid];

    f32x4 yacc[8];
    #pragma unroll
    for (int pf=0;pf<8;pf++) yacc[pf] = (f32x4){0.f,0.f,0.f,0.f};

    for (int s0 = 0; s0 <= l0; s0 += 64){
      __syncthreads();
      {
        int row = tid >> 2, c0 = (tid & 3) << 4;
        const short* src = &xBC[(size_t)(base + s0 + row)*512 + 256 + (h<<6) + c0];
        *reinterpret_cast<bf16x8*>(&Bbf[row*72 + c0])     = *reinterpret_cast<const bf16x8*>(src);
        *reinterpret_cast<bf16x8*>(&Bbf[row*72 + c0 + 8]) = *reinterpret_cast<const bf16x8*>(src+8);
      }
      {
        int s = tid >> 2;
        int p0 = (tid & 3) << 5;
        const short* src = &xBC[(size_t)(base + s0 + s)*512 + (h<<7) + p0];
        #pragma unroll
        for (int q=0;q<4;q++){
          bf16x8 v = *reinterpret_cast<const bf16x8*>(src + q*8);
          #pragma unroll
          for (int e=0;e<8;e++) Xt[(p0 + q*8 + e)*76 + s] = v[e];
        }
      }
      if (tid < 64){
        acs_s[tid] = acsrow[s0 + tid];
        dt_s[tid]  = dtb[(size_t)(base + s0 + tid)*2 + h];
      }
      __syncthreads();

      f32x4 sacc[4];
      #pragma unroll
      for (int f=0;f<4;f++) sacc[f] = (f32x4){0.f,0.f,0.f,0.f};
      bf16x8 ca0 = *reinterpret_cast<const bf16x8*>(&Cbf[(w*16+lr)*72 + lg*8]);
      bf16x8 ca1 = *reinterpret_cast<const bf16x8*>(&Cbf[(w*16+lr)*72 + 32 + lg*8]);
      #pragma unroll
      for (int f=0;f<4;f++){
        bf16x8 bb0 = *reinterpret_cast<const bf16x8*>(&Bbf[(f*16+lr)*72 + lg*8]);
        bf16x8 bb1 = *reinterpret_cast<const bf16x8*>(&Bbf[(f*16+lr)*72 + 32 + lg*8]);
        sacc[f] = __builtin_amdgcn_mfma_f32_16x16x32_bf16(ca0, bb0, sacc[f], 0, 0, 0);
        sacc[f] = __builtin_amdgcn_mfma_f32_16x16x32_bf16(ca1, bb1, sacc[f], 0, 0, 0);
      }
      #pragma unroll
      for (int f=0;f<4;f++){
        #pragma unroll
        for (int r=0;r<4;r++){
          int ll = w*16 + lg*4 + r;
          int ss = f*16 + lr;
          float v = 0.f;
          if (s0 + ss <= l0 + ll)
            v = sacc[f][r] * __expf(acs_l[ll] - acs_s[ss]) * dt_s[ss];
          Sbf[ll*72 + ss] = f2b(v);
        }
      }
      __syncthreads();

      bf16x8 sa0 = *reinterpret_cast<const bf16x8*>(&Sbf[(w*16+lr)*72 + lg*8]);
      bf16x8 sa1 = *reinterpret_cast<const bf16x8*>(&Sbf[(w*16+lr)*72 + 32 + lg*8]);
      #pragma unroll
      for (int pf=0;pf<8;pf++){
        bf16x8 x0 = *reinterpret_cast<const bf16x8*>(&Xt[(pf*16+lr)*76 + lg*8]);
        bf16x8 x1 = *reinterpret_cast<const bf16x8*>(&Xt[(pf*16+lr)*76 + 32 + lg*8]);
        yacc[pf] = __builtin_amdgcn_mfma_f32_16x16x32_bf16(sa0, x0, yacc[pf], 0, 0, 0);
        yacc[pf] = __builtin_amdgcn_mfma_f32_16x16x32_bf16(sa1, x1, yacc[pf], 0, 0, 0);
      }
    }

    // R term
    __syncthreads();
    {
      size_t roff = (((size_t)(b*16+ci)*2) + h) << 13;
      int n = tid >> 2;
      const float* src = R + roff + (size_t)n*128;
      #pragma unroll
      for (int j=0;j<8;j++){
        int p = ((tid & 3) << 2) + (j << 4);
        float4 f = *reinterpret_cast<const float4*>(&src[p]);
        Xt[(p+0)*76 + n] = f2b(f.x);
        Xt[(p+1)*76 + n] = f2b(f.y);
        Xt[(p+2)*76 + n] = f2b(f.z);
        Xt[(p+3)*76 + n] = f2b(f.w);
      }
    }
    __syncthreads();
    f32x4 racc[8];
    #pragma unroll
    for (int pf=0;pf<8;pf++) racc[pf] = (f32x4){0.f,0.f,0.f,0.f};
    {
      bf16x8 ca0 = *reinterpret_cast<const bf16x8*>(&Cbf[(w*16+lr)*72 + lg*8]);
      bf16x8 ca1 = *reinterpret_cast<const bf16x8*>(&Cbf[(w*16+lr)*72 + 32 + lg*8]);
      #pragma unroll
      for (int pf=0;pf<8;pf++){
        bf16x8 x0 = *reinterpret_cast<const bf16x8*>(&Xt[(pf*16+lr)*76 + lg*8]);
        bf16x8 x1 = *reinterpret_cast<const bf16x8*>(&Xt[(pf*16+lr)*76 + 32 + lg*8]);
        racc[pf] = __builtin_amdgcn_mfma_f32_16x16x32_bf16(ca0, x0, racc[pf], 0, 0, 0);
        racc[pf] = __builtin_amdgcn_mfma_f32_16x16x32_bf16(ca1, x1, racc[pf], 0, 0, 0);
      }
    }
    float Dh = Dp[h];
    float el[4];
    #pragma unroll
    for (int r=0;r<4;r++) el[r] = __expf(acs_l[w*16 + lg*4 + r]);
    #pragma unroll
    for (int pf=0;pf<8;pf++){
      f32x4 o;
      #pragma unroll
      for (int r=0;r<4;r++){
        int ll = w*16 + lg*4 + r;
        int p = pf*16 + lr;
        size_t pix = (size_t)(base + l0 + ll);
        float xraw = b2f(xBC[pix*512 + (h<<7) + p]);
        o[r] = yacc[pf][r] + el[r]*racc[pf][r] + Dh*xraw;
      }
      yv[pf] = o;
    }
  };

  f32x4 y0[8], y1[8];
  body(0, y0);
  body(1, y1);

  // RMSNorm across 256 channels per pixel (pixel = w*16+lg*4+r, values across lr x pf x h)
  f32x4 ss = (f32x4){0.f,0.f,0.f,0.f};
  #pragma unroll
  for (int pf=0;pf<8;pf++){
    #pragma unroll
    for (int r=0;r<4;r++)
      ss[r] += y0[pf][r]*y0[pf][r] + y1[pf][r]*y1[pf][r];
  }
  #pragma unroll
  for (int m=1; m<16; m<<=1){
    #pragma unroll
    for (int r=0;r<4;r++) ss[r] += __shfl_xor(ss[r], m);
  }
  f32x4 scale;
  #pragma unroll
  for (int r=0;r<4;r++) scale[r] = rsqrtf(ss[r]*(1.f/256.f) + 1e-5f);

  #pragma unroll
  for (int pf=0;pf<8;pf++){
    float nw0 = nw[pf*16 + lr];
    float nw1 = nw[128 + pf*16 + lr];
    #pragma unroll
    for (int r=0;r<4;r++){
      size_t pix = (size_t)(base + l0 + w*16 + lg*4 + r);
      ynorm[pix*256 + pf*16 + lr]        = f2b(y0[pf][r]*scale[r]*nw0);
      ynorm[pix*256 + 128 + pf*16 + lr]  = f2b(y1[pf][r]*scale[r]*nw1);
    }
  }
}

// =====================================================================================
extern "C" void kernel_launch(void* const* d_in, const int* in_sizes, int n_in,
                              void* d_out, int out_size, void* d_ws, size_t ws_size,
                              hipStream_t stream)
{
  (void)in_sizes; (void)n_in; (void)out_size; (void)ws_size;
  const float* u        = (const float*)d_in[0];
  const float* sc_w1    = (const float*)d_in[1];
  const float* sc_b1    = (const float*)d_in[2];
  const float* sc_wdw   = (const float*)d_in[3];
  const float* sc_bdw   = (const float*)d_in[4];
  const float* sc_w2    = (const float*)d_in[5];
  const float* sc_b2    = (const float*)d_in[6];
  const float* mc_w     = (const float*)d_in[7];
  const float* mc_b     = (const float*)d_in[8];
  const float* qkvW_w   = (const float*)d_in[9];
  const float* qkvW_b   = (const float*)d_in[10];
  const float* qkvH_w   = (const float*)d_in[11];
  const float* qkvH_b   = (const float*)d_in[12];
  const float* fuseW_w  = (const float*)d_in[13];
  const float* fuseW_b  = (const float*)d_in[14];
  const float* fuseH_w  = (const float*)d_in[15];
  const float* fuseH_b  = (const float*)d_in[16];
  const float* in_proj_w= (const float*)d_in[17];
  const float* conv1d_w = (const float*)d_in[18];
  const float* conv1d_b = (const float*)d_in[19];
  const float* dt_bias  = (const float*)d_in[20];
  const float* A_log    = (const float*)d_in[21];
  const float* Dp       = (const float*)d_in[22];
  const float* norm_w   = (const float*)d_in[23];
  const float* outp_w   = (const float*)d_in[24];
  const float* outp_b   = (const float*)d_in[25];

  char* wsb = (char*)d_ws;
  size_t off = 0;
  auto alloc = [&](size_t bytes){ void* p = wsb + off; off = (off + bytes + 255) & ~(size_t)255; return p; };
  short* wbf   = (short*)alloc((size_t)1246208*2);    // w_zx|w_sc2|w_qkvW|w_outp|wcomb|wi2
  float* bcomb = (float*)alloc(769*4);
  float* bi2   = (float*)alloc(514*4);
  float* bzx   = (float*)alloc(768*4);
  short* slotB = (short*)alloc((size_t)PTOT*776*2);   // z1(512) / qkvW(520) / merged(776) / xbcdt(520)
  short* slotC = (short*)alloc((size_t)PTOT*512*2);   // z1dw / xBC
  short* slotZ = (short*)alloc((size_t)PTOT*256*2);   // z
  short* slotE = (short*)alloc((size_t)PTOT*256*2);   // x1; later ynorm
  short* slotF = (short*)alloc((size_t)PTOT*256*2);   // xw/xh bf16
  float* slotS = (float*)alloc((size_t)4460000*4);    // SSD f32 scratch + attn ctx

  float* dtb     = slotS;                    // P*2      = 65536
  float* AcsG    = slotS + 65536;            // 65536
  float* AtotG   = slotS + 131072;           // 256
  float* statesB = slotS + 131328;           // 2097152
  float* Rb      = slotS + 131328 + 2097152; // 2097152
  float* ctxb    = slotS;                    // 512*256 f32 (attn phase only; before dtb is written)
  short* ynorm   = slotE;
  short* xwh     = slotF;

  // weight table (element offsets into wbf)
  short* w_zx   = wbf + 0;         // 768 x 512  [sc_w1 ; mc_w]
  short* w_sc2  = wbf + 393216;    // 256 x 512
  short* w_qkvW = wbf + 524288;    // 513 x 256
  short* w_outp = wbf + 655616;    // 512 x 512
  short* wcomb  = wbf + 917760;    // 769 x 256
  short* wi2    = wbf + 1114624;   // 514 x 256

  short* u_pm = (short*)d_out;  // d_out doubles as bf16 pixel-major u scratch
  float* out  = (float*)d_out;

  const int BIG = 1<<30;

  k_cvtw<<<3585, 256, 0, stream>>>(sc_w1, mc_w, sc_w2, qkvW_w, outp_w, wbf);
  k_wcomp<<<1286, 256, 0, stream>>>(qkvH_w, fuseW_w, fuseW_b, qkvH_b, in_proj_w, fuseH_w, fuseH_b,
                                    sc_b1, mc_b, wcomb, bcomb, wi2, bi2, bzx);
  k_transpose<<<dim3(128,8,8), dim3(32,8), 0, stream>>>(u, u_pm);

  // merged z1 + x1: N=768, dual output (z1 -> slotB ld512; x1 -> slotE ld256)
  k_gemm<1,0><<<dim3(256,6), 256, 0, stream>>>(u_pm, u_pm, BIG, 512, 512, w_zx, bzx,
                                               slotB, 768, 512, 512, 0, slotE, 512, 256);
  // z-branch
  k_dwconv3x3<<<dim3(256,4), 256, 0, stream>>>(slotB, sc_wdw, sc_bdw, slotC);
  k_gemm<1,0><<<dim3(256,2), 256, 0, stream>>>(slotC, slotC, BIG, 512, 512, w_sc2, sc_b2,
                                               slotZ, 256, 512, 256, 0, nullptr, BIG, 0);

  // x-branch: qkv W: [k|v|q] stride 520
  k_gemm<0,0><<<dim3(256,5), 256, 0, stream>>>(slotE, slotE, BIG, 256, 256, w_qkvW, qkvW_b,
                                               slotB, 513, 256, 520, 1, nullptr, BIG, 0);
  k_attn_ctx<<<512, 256, 0, stream>>>(slotB, 520, ctxb, 0);
  k_attn_apply<<<4096, 256, 0, stream>>>(slotE, 256, slotB, 520, ctxb, xwh, 0);
  // merged fuseW + (qkvH∘fuseW): [a2(256) | k|v|q(513)] stride 776
  k_gemm<0,0><<<dim3(256,7), 256, 0, stream>>>(xwh, xwh, BIG, 256, 256, wcomb, bcomb,
                                               slotB, 769, 256, 776, 0, nullptr, BIG, 0);
  k_attn_ctx<<<512, 256, 0, stream>>>(slotB + 256, 776, ctxb, 1);
  k_attn_apply<<<4096, 256, 0, stream>>>(slotB, 776, slotB + 256, 776, ctxb, xwh, 1);
  // composed in_proj: xbcdt [xBC(512) | dt(2)] stride 520
  k_gemm<0,0><<<dim3(256,5), 256, 0, stream>>>(xwh, xwh, BIG, 256, 256, wi2, bi2,
                                               slotB, 514, 256, 520, 0, nullptr, BIG, 0);
  k_dt<<<256, 256, 0, stream>>>(slotB, dt_bias, dtb);
  k_conv1d<<<1024, 256, 0, stream>>>(slotB, conv1d_w, conv1d_b, slotC);

  // SSD
  k_ssd_states<<<dim3(16,2,8), 256, 0, stream>>>(slotC, dtb, A_log, statesB, AcsG, AtotG);
  k_ssd_scan<<<16, 256, 0, stream>>>(statesB, AtotG, Rb);
  k_ssd_y_norm<<<dim3(64,8), 256, 0, stream>>>(slotC, dtb, AcsG, Rb, Dp, norm_w, ynorm);

  // final: out = concat(z, ynorm) @ outp_w^T + b, written f32 NCHW into d_out
  k_gemm<0,1><<<dim3(256,4), 256, 0, stream>>>(slotZ, ynorm, 256, 256, 256, w_outp, outp_b,
                                               out, 512, 512, 512, 0, nullptr, BIG, 0);
}